// Round 2
// baseline (1111.386 us; speedup 1.0000x reference)
//
#include <hip/hip_runtime.h>
#include <hip/hip_bf16.h>

// SplineCNN: 2x spline conv (max aggregation) + final linear.
// N=50000 nodes, E=800000 edges, C=64, 5x5 kernel grid (25), degree-1 B-spline.
//
// Round 2: workspace-adaptive chunking. Round 1 faulted (core dump) most
// likely because the 371 MB workspace layout exceeded ws_size. Now:
//   ws: agg[N,64] | x1[N,64] | xRoot[N,64] | xW_chunk[chunk_rows,1600]
// chunk_rows is derived from ws_size. Edges are processed once per chunk,
// guarded by (src in chunk) — wave-per-edge, so the guard is wave-uniform.
// x2 lives in d_out (node_post writes it; final_gemm reads each row before
// writing it, per-block, so in-place is safe).

__device__ __forceinline__ void atomicMaxF(float* addr, float v) {
    // IEEE trick: >=0 monotone in int bits; <0 monotone-decreasing in uint bits.
    if (v >= 0.f) atomicMax((int*)addr, __float_as_int(v));
    else          atomicMin((unsigned int*)addr, __float_as_uint(v));
}

// ---------------- GEMM: out[m, bx*64 + o] = sum_i A[m,i] * B[bx][i,o] ----
// A: [M,64] rows. B: gridDim.x contiguous 64x64 tiles. out row stride ldC.
__global__ __launch_bounds__(256) void gemm_tiles(
    const float* __restrict__ A, const float* __restrict__ B,
    float* __restrict__ out, int M, int ldC)
{
    __shared__ float As[64][68];   // As[k][m] (transposed A tile)
    __shared__ float Bs[64][68];   // Bs[k][o]
    const int bx = blockIdx.x;
    const int m0 = blockIdx.y * 64;
    const int tid = threadIdx.x;
    const float* Bt = B + (size_t)bx * 4096;

    {   // load B tile: 4096 floats = 1024 float4, 4 per thread
        const float4* B4 = (const float4*)Bt;
        #pragma unroll
        for (int r = 0; r < 4; ++r) {
            int idx = tid + r * 256;
            float4 v = B4[idx];
            int i = idx >> 4;
            int o = (idx & 15) * 4;
            Bs[i][o] = v.x; Bs[i][o + 1] = v.y; Bs[i][o + 2] = v.z; Bs[i][o + 3] = v.w;
        }
    }
    {   // load A tile transposed
        #pragma unroll
        for (int r = 0; r < 4; ++r) {
            int idx = tid + r * 256;
            int m = idx >> 4;
            int k = (idx & 15) * 4;
            int gm = m0 + m;
            float4 v = make_float4(0.f, 0.f, 0.f, 0.f);
            if (gm < M) v = *(const float4*)(A + (size_t)gm * 64 + k);
            As[k][m] = v.x; As[k + 1][m] = v.y; As[k + 2][m] = v.z; As[k + 3][m] = v.w;
        }
    }
    __syncthreads();

    const int tx = tid & 15, ty = tid >> 4;
    float acc[4][4] = {};
    #pragma unroll 8
    for (int k = 0; k < 64; ++k) {
        float4 av = *(const float4*)&As[k][ty * 4];
        float4 bv = *(const float4*)&Bs[k][tx * 4];
        float aa[4] = {av.x, av.y, av.z, av.w};
        float bb[4] = {bv.x, bv.y, bv.z, bv.w};
        #pragma unroll
        for (int i = 0; i < 4; ++i)
            #pragma unroll
            for (int j = 0; j < 4; ++j)
                acc[i][j] = fmaf(aa[i], bb[j], acc[i][j]);
    }

    const int c0 = bx * 64;
    #pragma unroll
    for (int i = 0; i < 4; ++i) {
        int gm = m0 + ty * 4 + i;
        if (gm < M) {
            float4 v = make_float4(acc[i][0], acc[i][1], acc[i][2], acc[i][3]);
            *(float4*)(out + (size_t)gm * ldC + c0 + tx * 4) = v;
        }
    }
}

// ---------------- fill agg with -inf ------------------------------------
__global__ __launch_bounds__(256) void fill_neginf(float* __restrict__ p, int n)
{
    int i = blockIdx.x * 256 + threadIdx.x;
    if (i < n) p[i] = -__builtin_inff();
}

// ---------------- edge gather + atomic max (chunked over src) -----------
// xWc: [rows, 1600] = xW for src in [base, base+rows). Wave per edge.
__global__ __launch_bounds__(256) void edge_agg(
    const float* __restrict__ xWc, const int* __restrict__ ei,
    const float* __restrict__ attr, float* __restrict__ agg,
    int E, int base, int rows)
{
    int w = blockIdx.x * 4 + (threadIdx.x >> 6);   // edge id (wave per edge)
    int lane = threadIdx.x & 63;                   // channel
    if (w >= E) return;
    int src = ei[w];
    int rel = src - base;
    if (rel < 0 || rel >= rows) return;            // wave-uniform exit
    int dst = ei[E + w];
    float u = attr[2 * w] * 4.f;
    float v = attr[2 * w + 1] * 4.f;
    float lu = floorf(u), lv = floorf(v);
    float fu = u - lu, fv = v - lv;
    int iu = (int)lu;  iu = iu < 0 ? 0 : (iu > 4 ? 4 : iu);
    int iv = (int)lv;  iv = iv < 0 ? 0 : (iv > 4 ? 4 : iv);
    int iu1 = iu + 1 > 4 ? 4 : iu + 1;
    int iv1 = iv + 1 > 4 ? 4 : iv + 1;

    const float* row = xWc + (size_t)rel * 1600;
    float m;
    m = (1.f - fu) * (1.f - fv) * row[(iu  + 5 * iv ) * 64 + lane];
    m = fmaf((1.f - fu) * fv,     row[(iu  + 5 * iv1) * 64 + lane], m);
    m = fmaf(fu * (1.f - fv),     row[(iu1 + 5 * iv ) * 64 + lane], m);
    m = fmaf(fu * fv,             row[(iu1 + 5 * iv1) * 64 + lane], m);

    atomicMaxF(&agg[(size_t)dst * 64 + lane], m);
}

// ---------------- node post: fix -inf, + root + bias, relu --------------
__global__ __launch_bounds__(256) void node_post(
    const float* __restrict__ agg, const float* __restrict__ xRoot,
    const float* __restrict__ bias, float* __restrict__ out, int N)
{
    int n = blockIdx.x * 4 + (threadIdx.x >> 6);
    int lane = threadIdx.x & 63;
    if (n >= N) return;
    float a = agg[(size_t)n * 64 + lane];
    if (a == -__builtin_inff()) a = 0.f;
    float val = a + xRoot[(size_t)n * 64 + lane] + bias[lane];
    out[(size_t)n * 64 + lane] = fmaxf(val, 0.f);
}

// ---------------- final: out = [x|x1|x2] @ fw + fb ----------------------
// x2 == out (in-place): each block reads only its own rows (kt=2) before
// writing them, so this is safe.
__global__ __launch_bounds__(256) void final_gemm(
    const float* __restrict__ x, const float* __restrict__ x1,
    const float* __restrict__ x2, const float* __restrict__ fw,
    const float* __restrict__ fb, float* __restrict__ out, int M)
{
    __shared__ float As[64][68];
    __shared__ float Bs[64][68];
    const int m0 = blockIdx.x * 64;
    const int tid = threadIdx.x;
    const int tx = tid & 15, ty = tid >> 4;
    float acc[4][4] = {};
    const float* srcs[3] = {x, x1, x2};

    for (int kt = 0; kt < 3; ++kt) {
        const float* A = srcs[kt];
        const float4* B4 = (const float4*)(fw + (size_t)kt * 4096);
        #pragma unroll
        for (int r = 0; r < 4; ++r) {
            int idx = tid + r * 256;
            float4 v = B4[idx];
            int i = idx >> 4;
            int o = (idx & 15) * 4;
            Bs[i][o] = v.x; Bs[i][o + 1] = v.y; Bs[i][o + 2] = v.z; Bs[i][o + 3] = v.w;
        }
        #pragma unroll
        for (int r = 0; r < 4; ++r) {
            int idx = tid + r * 256;
            int m = idx >> 4;
            int k = (idx & 15) * 4;
            int gm = m0 + m;
            float4 v = make_float4(0.f, 0.f, 0.f, 0.f);
            if (gm < M) v = *(const float4*)(A + (size_t)gm * 64 + k);
            As[k][m] = v.x; As[k + 1][m] = v.y; As[k + 2][m] = v.z; As[k + 3][m] = v.w;
        }
        __syncthreads();
        #pragma unroll 8
        for (int k = 0; k < 64; ++k) {
            float4 av = *(const float4*)&As[k][ty * 4];
            float4 bv = *(const float4*)&Bs[k][tx * 4];
            float aa[4] = {av.x, av.y, av.z, av.w};
            float bb[4] = {bv.x, bv.y, bv.z, bv.w};
            #pragma unroll
            for (int i = 0; i < 4; ++i)
                #pragma unroll
                for (int j = 0; j < 4; ++j)
                    acc[i][j] = fmaf(aa[i], bb[j], acc[i][j]);
        }
        __syncthreads();
    }

    #pragma unroll
    for (int i = 0; i < 4; ++i) {
        int gm = m0 + ty * 4 + i;
        if (gm < M) {
            float4 v = make_float4(acc[i][0] + fb[tx * 4 + 0],
                                   acc[i][1] + fb[tx * 4 + 1],
                                   acc[i][2] + fb[tx * 4 + 2],
                                   acc[i][3] + fb[tx * 4 + 3]);
            *(float4*)(out + (size_t)gm * 64 + tx * 4) = v;
        }
    }
}

extern "C" void kernel_launch(void* const* d_in, const int* in_sizes, int n_in,
                              void* d_out, int out_size, void* d_ws, size_t ws_size,
                              hipStream_t stream)
{
    const float* x    = (const float*)d_in[0];
    const int*   ei   = (const int*)d_in[1];
    const float* attr = (const float*)d_in[2];
    const float* W1   = (const float*)d_in[3];
    const float* r1   = (const float*)d_in[4];
    const float* b1   = (const float*)d_in[5];
    const float* W2   = (const float*)d_in[6];
    const float* r2   = (const float*)d_in[7];
    const float* b2   = (const float*)d_in[8];
    const float* fw   = (const float*)d_in[9];
    const float* fb   = (const float*)d_in[10];
    float* out = (float*)d_out;

    const int N = in_sizes[0] / 64;
    const int E = in_sizes[1] / 2;

    // ws layout (fp32): agg[N,64] | x1[N,64] | xRoot[N,64] | xW_chunk[chunk_rows,1600]
    float* agg   = (float*)d_ws;
    float* x1    = agg + (size_t)N * 64;
    float* xRoot = x1 + (size_t)N * 64;
    float* xWc   = xRoot + (size_t)N * 64;

    const size_t fixed_bytes = (size_t)3 * N * 64 * sizeof(float);
    size_t avail = ws_size > fixed_bytes ? ws_size - fixed_bytes : 0;
    long long max_rows = (long long)(avail / (1600 * sizeof(float)));
    int chunk_rows = (max_rows >= N) ? N : (int)((max_rows / 64) * 64);
    if (chunk_rows < 64) chunk_rows = 64;   // last resort; below this nothing fits
    const int nchunks = (N + chunk_rows - 1) / chunk_rows;

    const int fgrid = (N * 64 + 255) / 256;
    const int egrid = (E + 3) / 4;
    const int ngrid = (N + 3) / 4;
    const int rgrid = (N + 63) / 64;

    const float* xin = x;
    const float* Ws[2] = {W1, W2};
    const float* rs[2] = {r1, r2};
    const float* bs[2] = {b1, b2};
    float* xo[2] = {x1, out};   // x2 lives in d_out

    for (int layer = 0; layer < 2; ++layer) {
        // xRoot = xin @ root
        gemm_tiles<<<dim3(1, rgrid), 256, 0, stream>>>(xin, rs[layer], xRoot, N, 64);
        fill_neginf<<<fgrid, 256, 0, stream>>>(agg, N * 64);
        for (int c = 0; c < nchunks; ++c) {
            int base = c * chunk_rows;
            int rows = (base + chunk_rows <= N) ? chunk_rows : (N - base);
            gemm_tiles<<<dim3(25, (rows + 63) / 64), 256, 0, stream>>>(
                xin + (size_t)base * 64, Ws[layer], xWc, rows, 1600);
            edge_agg<<<egrid, 256, 0, stream>>>(xWc, ei, attr, agg, E, base, rows);
        }
        node_post<<<ngrid, 256, 0, stream>>>(agg, xRoot, bs[layer], xo[layer], N);
        xin = xo[layer];
    }

    // final: out = [x | x1 | x2(=out)] @ fw + fb  (in-place safe)
    final_gemm<<<(N + 63) / 64, 256, 0, stream>>>(x, x1, out, fw, fb, out, N);
}

// Round 3
// 589.940 us; speedup vs baseline: 1.8839x; 1.8839x over previous
//
#include <hip/hip_runtime.h>
#include <hip/hip_bf16.h>

// SplineCNN round 3: bf16 xW (L3-resident) + CSR-by-dst (no atomics in the
// hot pass) + bf16 MFMA GEMMs + fused node epilogue.
//
// Round-2 evidence: nchunks==1 => ws_size >= 358 MB; this layout needs ~220 MB.
// edge_agg was 2x222us with FETCH=320MB (fp32 xW > L3) and WRITE=286MB
// (atomic write-through). Both are addressed structurally here.

typedef short  bf16x8 __attribute__((ext_vector_type(8)));
typedef float  f32x4  __attribute__((ext_vector_type(4)));

__device__ __forceinline__ float bf2f(ushort u) {
    return __uint_as_float((uint)u << 16);
}
__device__ __forceinline__ ushort f2bf(float f) {   // round-to-nearest-even
    uint u = __float_as_uint(f);
    return (ushort)((u + 0x7FFF + ((u >> 16) & 1)) >> 16);
}

// ---------------- converts ----------------------------------------------
__global__ __launch_bounds__(256) void cvt_f32_bf16(
    const float* __restrict__ in, ushort* __restrict__ out, int n)
{
    int i = blockIdx.x * 256 + threadIdx.x;
    if (i < n) out[i] = f2bf(in[i]);
}

// W[25][i][o] + root[i][o] (fp32) -> Wt[26][o][i] (bf16)
__global__ __launch_bounds__(256) void cvt_WT(
    const float* __restrict__ W, const float* __restrict__ root,
    ushort* __restrict__ Wt)
{
    int idx = blockIdx.x * 256 + threadIdx.x;
    if (idx >= 26 * 4096) return;
    int tile = idx >> 12, rem = idx & 4095, o = rem >> 6, i = rem & 63;
    float v = (tile < 25) ? W[tile * 4096 + i * 64 + o] : root[i * 64 + o];
    Wt[idx] = f2bf(v);
}

// ---------------- CSR build ---------------------------------------------
__global__ __launch_bounds__(256) void zero_ints(int* __restrict__ p, int n)
{
    int i = blockIdx.x * 256 + threadIdx.x;
    if (i < n) p[i] = 0;
}

__global__ __launch_bounds__(256) void hist_deg(
    const int* __restrict__ ei, int* __restrict__ deg, int E)
{
    int e = blockIdx.x * 256 + threadIdx.x;
    if (e < E) atomicAdd(&deg[ei[E + e]], 1);
}

__global__ __launch_bounds__(1024) void scan_block(
    const int* __restrict__ deg, int* __restrict__ inc,
    int* __restrict__ partial, int N)
{
    __shared__ int s[1024];
    int i = blockIdx.x * 1024 + threadIdx.x;
    int v = (i < N) ? deg[i] : 0;
    s[threadIdx.x] = v;
    __syncthreads();
    for (int off = 1; off < 1024; off <<= 1) {
        int t = (threadIdx.x >= off) ? s[threadIdx.x - off] : 0;
        __syncthreads();
        s[threadIdx.x] += t;
        __syncthreads();
    }
    if (i < N) inc[i] = s[threadIdx.x];
    if (threadIdx.x == 1023) partial[blockIdx.x] = s[1023];
}

__global__ void scan_partial(int* __restrict__ partial, int nb)  // nb <= 64
{
    __shared__ int s[64];
    int t = threadIdx.x;
    int v = (t < nb) ? partial[t] : 0;
    s[t] = v;
    __syncthreads();
    for (int off = 1; off < 64; off <<= 1) {
        int x = (t >= off) ? s[t - off] : 0;
        __syncthreads();
        s[t] += x;
        __syncthreads();
    }
    if (t < nb) partial[t] = s[t] - v;   // exclusive block offsets
}

__global__ __launch_bounds__(1024) void scan_finalize(
    const int* __restrict__ deg, const int* __restrict__ inc,
    const int* __restrict__ partial, int* __restrict__ row_ptr,
    int* __restrict__ cursor, int N)
{
    int i = blockIdx.x * 1024 + threadIdx.x;
    if (i >= N) return;
    int v = inc[i] + partial[blockIdx.x];
    row_ptr[i + 1] = v;
    cursor[i] = v - deg[i];
    if (i == 0) row_ptr[0] = 0;
}

// per-edge: compute spline basis/wi once (layer-independent), scatter into CSR
__global__ __launch_bounds__(256) void csr_scatter(
    const int* __restrict__ ei, const float* __restrict__ attr,
    int* __restrict__ cursor, int* __restrict__ esrc,
    uint* __restrict__ ewi, float4* __restrict__ ebasis, int E)
{
    int e = blockIdx.x * 256 + threadIdx.x;
    if (e >= E) return;
    int src = ei[e], dst = ei[E + e];
    float u = attr[2 * e] * 4.f;
    float v = attr[2 * e + 1] * 4.f;
    float lu = floorf(u), lv = floorf(v);
    float fu = u - lu, fv = v - lv;
    int iu = (int)lu;  iu = iu < 0 ? 0 : (iu > 4 ? 4 : iu);
    int iv = (int)lv;  iv = iv < 0 ? 0 : (iv > 4 ? 4 : iv);
    int iu1 = iu + 1 > 4 ? 4 : iu + 1;
    int iv1 = iv + 1 > 4 ? 4 : iv + 1;
    // flat order matches reference reshape: (u0,v0),(u0,v1),(u1,v0),(u1,v1)
    uint wp = (uint)(iu + 5 * iv) | ((uint)(iu + 5 * iv1) << 8) |
              ((uint)(iu1 + 5 * iv) << 16) | ((uint)(iu1 + 5 * iv1) << 24);
    int pos = atomicAdd(&cursor[dst], 1);
    esrc[pos] = src;
    ewi[pos] = wp;
    ebasis[pos] = make_float4((1.f - fu) * (1.f - fv), (1.f - fu) * fv,
                              fu * (1.f - fv), fu * fv);
}

// ---------------- MFMA GEMM: out = A @ Bt^T per 64-col tile -------------
// A: [Mpad][64] bf16 rows. Bt: [tiles][o][i] bf16. Grid (ntiles, Mpad/64).
// Fragment maps (guide m89/m91-verified):
//   A[m][k]: m=lane&15, k=(lane>>4)*8+j ; B[k][n]: n=lane&15, k=(lane>>4)*8+j
//   C/D:     col=lane&15, row=(lane>>4)*4+reg
template<bool BF16OUT>
__global__ __launch_bounds__(256) void gemm_mfma(
    const ushort* __restrict__ A, const ushort* __restrict__ Bt,
    void* __restrict__ out, int M, int ldC)
{
    const int bx = blockIdx.x;
    const int wave = threadIdx.x >> 6;
    const int lane = threadIdx.x & 63;
    const int l16 = lane & 15;
    const int half = lane >> 4;                 // 0..3
    const int m_base = blockIdx.y * 64 + wave * 16;

    const ushort* arow = A + (size_t)(m_base + l16) * 64;
    bf16x8 a0 = *(const bf16x8*)(arow + half * 8);
    bf16x8 a1 = *(const bf16x8*)(arow + 32 + half * 8);

    const ushort* btile = Bt + (size_t)bx * 4096;
    f32x4 acc[4];
    #pragma unroll
    for (int s = 0; s < 4; ++s) {
        acc[s] = (f32x4){0.f, 0.f, 0.f, 0.f};
        const ushort* brow = btile + (size_t)(s * 16 + l16) * 64;
        bf16x8 b0 = *(const bf16x8*)(brow + half * 8);
        bf16x8 b1 = *(const bf16x8*)(brow + 32 + half * 8);
        acc[s] = __builtin_amdgcn_mfma_f32_16x16x32_bf16(a0, b0, acc[s], 0, 0, 0);
        acc[s] = __builtin_amdgcn_mfma_f32_16x16x32_bf16(a1, b1, acc[s], 0, 0, 0);
    }

    #pragma unroll
    for (int s = 0; s < 4; ++s) {
        int o = bx * 64 + s * 16 + l16;
        #pragma unroll
        for (int r = 0; r < 4; ++r) {
            int m = m_base + half * 4 + r;
            if (m < M) {
                if (BF16OUT) ((ushort*)out)[(size_t)m * ldC + o] = f2bf(acc[s][r]);
                else         ((float*)out)[(size_t)m * ldC + o] = acc[s][r];
            }
        }
    }
}

// ---------------- edge pass: wave per dst, fused node epilogue ----------
__global__ __launch_bounds__(256) void edge_csr(
    const ushort* __restrict__ xWb, const int* __restrict__ row_ptr,
    const int* __restrict__ esrc, const uint* __restrict__ ewi,
    const float4* __restrict__ ebasis, const float* __restrict__ xRoot,
    const float* __restrict__ bias, float* __restrict__ outf,
    ushort* __restrict__ outb, int N)
{
    int d = blockIdx.x * 4 + (threadIdx.x >> 6);
    int lane = threadIdx.x & 63;
    if (d >= N) return;
    int e0 = row_ptr[d], e1 = row_ptr[d + 1];
    float vmax = -__builtin_inff();
    for (int e = e0; e < e1; ++e) {
        int src = esrc[e];
        uint wp = ewi[e];
        float4 b = ebasis[e];
        const ushort* row = xWb + (size_t)src * 1600;
        float m = b.x * bf2f(row[(wp & 31) * 64 + lane]);
        m = fmaf(b.y, bf2f(row[((wp >> 8) & 31) * 64 + lane]), m);
        m = fmaf(b.z, bf2f(row[((wp >> 16) & 31) * 64 + lane]), m);
        m = fmaf(b.w, bf2f(row[(wp >> 24) * 64 + lane]), m);
        vmax = fmaxf(vmax, m);
    }
    if (e1 == e0) vmax = 0.f;          // segment_max(-inf) -> 0
    float val = vmax + xRoot[(size_t)d * 64 + lane] + bias[lane];
    val = fmaxf(val, 0.f);
    outf[(size_t)d * 64 + lane] = val;
    if (outb) outb[(size_t)d * 64 + lane] = f2bf(val);
}

// ---------------- final: out = [x|x1|x2] @ fw + fb (fp32, as round 2) ---
__global__ __launch_bounds__(256) void final_gemm(
    const float* __restrict__ x, const float* __restrict__ x1,
    const float* __restrict__ x2, const float* __restrict__ fw,
    const float* __restrict__ fb, float* __restrict__ out, int M)
{
    __shared__ float As[64][68];
    __shared__ float Bs[64][68];
    const int m0 = blockIdx.x * 64;
    const int tid = threadIdx.x;
    const int tx = tid & 15, ty = tid >> 4;
    float acc[4][4] = {};
    const float* srcs[3] = {x, x1, x2};

    for (int kt = 0; kt < 3; ++kt) {
        const float* A = srcs[kt];
        const float4* B4 = (const float4*)(fw + (size_t)kt * 4096);
        #pragma unroll
        for (int r = 0; r < 4; ++r) {
            int idx = tid + r * 256;
            float4 v = B4[idx];
            int i = idx >> 4;
            int o = (idx & 15) * 4;
            Bs[i][o] = v.x; Bs[i][o + 1] = v.y; Bs[i][o + 2] = v.z; Bs[i][o + 3] = v.w;
        }
        #pragma unroll
        for (int r = 0; r < 4; ++r) {
            int idx = tid + r * 256;
            int m = idx >> 4;
            int k = (idx & 15) * 4;
            int gm = m0 + m;
            float4 v = make_float4(0.f, 0.f, 0.f, 0.f);
            if (gm < M) v = *(const float4*)(A + (size_t)gm * 64 + k);
            As[k][m] = v.x; As[k + 1][m] = v.y; As[k + 2][m] = v.z; As[k + 3][m] = v.w;
        }
        __syncthreads();
        #pragma unroll 8
        for (int k = 0; k < 64; ++k) {
            float4 av = *(const float4*)&As[k][ty * 4];
            float4 bv = *(const float4*)&Bs[k][tx * 4];
            float aa[4] = {av.x, av.y, av.z, av.w};
            float bb[4] = {bv.x, bv.y, bv.z, bv.w};
            #pragma unroll
            for (int i = 0; i < 4; ++i)
                #pragma unroll
                for (int j = 0; j < 4; ++j)
                    acc[i][j] = fmaf(aa[i], bb[j], acc[i][j]);
        }
        __syncthreads();
    }

    #pragma unroll
    for (int i = 0; i < 4; ++i) {
        int gm = m0 + ty * 4 + i;
        if (gm < M) {
            float4 v = make_float4(acc[i][0] + fb[tx * 4 + 0],
                                   acc[i][1] + fb[tx * 4 + 1],
                                   acc[i][2] + fb[tx * 4 + 2],
                                   acc[i][3] + fb[tx * 4 + 3]);
            *(float4*)(out + (size_t)gm * 64 + tx * 4) = v;
        }
    }
}

extern "C" void kernel_launch(void* const* d_in, const int* in_sizes, int n_in,
                              void* d_out, int out_size, void* d_ws, size_t ws_size,
                              hipStream_t stream)
{
    const float* x    = (const float*)d_in[0];
    const int*   ei   = (const int*)d_in[1];
    const float* attr = (const float*)d_in[2];
    const float* W1   = (const float*)d_in[3];
    const float* r1   = (const float*)d_in[4];
    const float* b1   = (const float*)d_in[5];
    const float* W2   = (const float*)d_in[6];
    const float* r2   = (const float*)d_in[7];
    const float* b2   = (const float*)d_in[8];
    const float* fw   = (const float*)d_in[9];
    const float* fb   = (const float*)d_in[10];
    float* out = (float*)d_out;

    const int N = in_sizes[0] / 64;
    const int E = in_sizes[1] / 2;
    const int mtiles = (N + 63) / 64;
    const int Npad = mtiles * 64;

    // workspace carve (~220 MB; round-2 evidence: ws_size >= 358 MB)
    char* p = (char*)d_ws;
    auto alloc = [&](size_t bytes) { void* q = p; p += (bytes + 255) & ~(size_t)255; return q; };
    float4* ebasis = (float4*)alloc((size_t)E * 16);
    float*  x1f    = (float*)alloc((size_t)Npad * 64 * 4);
    float*  xRoot  = (float*)alloc((size_t)Npad * 64 * 4);
    ushort* xWb    = (ushort*)alloc((size_t)Npad * 1600 * 2);
    ushort* xb     = (ushort*)alloc((size_t)Npad * 64 * 2);
    ushort* x1b    = (ushort*)alloc((size_t)Npad * 64 * 2);
    ushort* WtA    = (ushort*)alloc((size_t)26 * 4096 * 2);
    ushort* WtB    = (ushort*)alloc((size_t)26 * 4096 * 2);
    int*    esrc   = (int*)alloc((size_t)E * 4);
    uint*   ewi    = (uint*)alloc((size_t)E * 4);
    int*    deg    = (int*)alloc((size_t)N * 4);
    int*    cursor = (int*)alloc((size_t)N * 4);
    int*    rowp   = (int*)alloc((size_t)(N + 1) * 4);
    int*    tmpinc = (int*)alloc((size_t)N * 4);
    int*    part   = (int*)alloc(64 * 4);

    const int nb = (N + 1023) / 1024;   // <= 64 for N <= 65536

    // converts (once per call)
    cvt_f32_bf16<<<(N * 64 + 255) / 256, 256, 0, stream>>>(x, xb, N * 64);
    cvt_WT<<<(26 * 4096 + 255) / 256, 256, 0, stream>>>(W1, r1, WtA);
    cvt_WT<<<(26 * 4096 + 255) / 256, 256, 0, stream>>>(W2, r2, WtB);

    // CSR build (once per call, reused by both layers)
    zero_ints<<<(N + 255) / 256, 256, 0, stream>>>(deg, N);
    hist_deg<<<(E + 255) / 256, 256, 0, stream>>>(ei, deg, E);
    scan_block<<<nb, 1024, 0, stream>>>(deg, tmpinc, part, N);
    scan_partial<<<1, 64, 0, stream>>>(part, nb);
    scan_finalize<<<nb, 1024, 0, stream>>>(deg, tmpinc, part, rowp, cursor, N);
    csr_scatter<<<(E + 255) / 256, 256, 0, stream>>>(ei, attr, cursor, esrc, ewi, ebasis, E);

    // layer 1
    gemm_mfma<true ><<<dim3(25, mtiles), 256, 0, stream>>>(xb, WtA, xWb, N, 1600);
    gemm_mfma<false><<<dim3(1,  mtiles), 256, 0, stream>>>(xb, WtA + 25 * 4096, xRoot, N, 64);
    edge_csr<<<(N + 3) / 4, 256, 0, stream>>>(xWb, rowp, esrc, ewi, ebasis, xRoot, b1, x1f, x1b, N);

    // layer 2 (x2 lives in d_out; final reads rows before writing them)
    gemm_mfma<true ><<<dim3(25, mtiles), 256, 0, stream>>>(x1b, WtB, xWb, N, 1600);
    gemm_mfma<false><<<dim3(1,  mtiles), 256, 0, stream>>>(x1b, WtB + 25 * 4096, xRoot, N, 64);
    edge_csr<<<(N + 3) / 4, 256, 0, stream>>>(xWb, rowp, esrc, ewi, ebasis, xRoot, b2, out, nullptr, N);

    // final
    final_gemm<<<mtiles, 256, 0, stream>>>(x, x1f, out, fw, fb, out, N);
}

// Round 4
// 570.026 us; speedup vs baseline: 1.9497x; 1.0349x over previous
//
#include <hip/hip_runtime.h>
#include <hip/hip_bf16.h>

// SplineCNN round 4: fix the write-bound xW GEMM.
// Round-3 evidence: gemm_mfma 105us x2, WRITE=156MB at 1.78 TB/s — scalar
// ushort stores (4 rows x 32B fragments per wave-store). Now: stage the
// 64x64 bf16 C-tile in LDS and store uint4 (128B-line granular). Root GEMM
// merged into the same dispatch as tile 25 (fp32 path).

typedef short  bf16x8 __attribute__((ext_vector_type(8)));
typedef float  f32x4  __attribute__((ext_vector_type(4)));

__device__ __forceinline__ float bf2f(ushort u) {
    return __uint_as_float((uint)u << 16);
}
__device__ __forceinline__ ushort f2bf(float f) {   // round-to-nearest-even
    uint u = __float_as_uint(f);
    return (ushort)((u + 0x7FFF + ((u >> 16) & 1)) >> 16);
}

// ---------------- converts ----------------------------------------------
__global__ __launch_bounds__(256) void cvt_f32_bf16(
    const float* __restrict__ in, ushort* __restrict__ out, int n)
{
    int i = blockIdx.x * 256 + threadIdx.x;
    if (i < n) out[i] = f2bf(in[i]);
}

// W[25][i][o] + root[i][o] (fp32) -> Wt[26][o][i] (bf16)
__global__ __launch_bounds__(256) void cvt_WT(
    const float* __restrict__ W, const float* __restrict__ root,
    ushort* __restrict__ Wt)
{
    int idx = blockIdx.x * 256 + threadIdx.x;
    if (idx >= 26 * 4096) return;
    int tile = idx >> 12, rem = idx & 4095, o = rem >> 6, i = rem & 63;
    float v = (tile < 25) ? W[tile * 4096 + i * 64 + o] : root[i * 64 + o];
    Wt[idx] = f2bf(v);
}

// ---------------- CSR build ---------------------------------------------
__global__ __launch_bounds__(256) void zero_ints(int* __restrict__ p, int n)
{
    int i = blockIdx.x * 256 + threadIdx.x;
    if (i < n) p[i] = 0;
}

__global__ __launch_bounds__(256) void hist_deg(
    const int* __restrict__ ei, int* __restrict__ deg, int E)
{
    int e = blockIdx.x * 256 + threadIdx.x;
    if (e < E) atomicAdd(&deg[ei[E + e]], 1);
}

__global__ __launch_bounds__(1024) void scan_block(
    const int* __restrict__ deg, int* __restrict__ inc,
    int* __restrict__ partial, int N)
{
    __shared__ int s[1024];
    int i = blockIdx.x * 1024 + threadIdx.x;
    int v = (i < N) ? deg[i] : 0;
    s[threadIdx.x] = v;
    __syncthreads();
    for (int off = 1; off < 1024; off <<= 1) {
        int t = (threadIdx.x >= off) ? s[threadIdx.x - off] : 0;
        __syncthreads();
        s[threadIdx.x] += t;
        __syncthreads();
    }
    if (i < N) inc[i] = s[threadIdx.x];
    if (threadIdx.x == 1023) partial[blockIdx.x] = s[1023];
}

__global__ void scan_partial(int* __restrict__ partial, int nb)  // nb <= 64
{
    __shared__ int s[64];
    int t = threadIdx.x;
    int v = (t < nb) ? partial[t] : 0;
    s[t] = v;
    __syncthreads();
    for (int off = 1; off < 64; off <<= 1) {
        int x = (t >= off) ? s[t - off] : 0;
        __syncthreads();
        s[t] += x;
        __syncthreads();
    }
    if (t < nb) partial[t] = s[t] - v;   // exclusive block offsets
}

__global__ __launch_bounds__(1024) void scan_finalize(
    const int* __restrict__ deg, const int* __restrict__ inc,
    const int* __restrict__ partial, int* __restrict__ row_ptr,
    int* __restrict__ cursor, int N)
{
    int i = blockIdx.x * 1024 + threadIdx.x;
    if (i >= N) return;
    int v = inc[i] + partial[blockIdx.x];
    row_ptr[i + 1] = v;
    cursor[i] = v - deg[i];
    if (i == 0) row_ptr[0] = 0;
}

// per-edge: compute spline basis/wi once (layer-independent), scatter into CSR
__global__ __launch_bounds__(256) void csr_scatter(
    const int* __restrict__ ei, const float* __restrict__ attr,
    int* __restrict__ cursor, int* __restrict__ esrc,
    uint* __restrict__ ewi, float4* __restrict__ ebasis, int E)
{
    int e = blockIdx.x * 256 + threadIdx.x;
    if (e >= E) return;
    int src = ei[e], dst = ei[E + e];
    float u = attr[2 * e] * 4.f;
    float v = attr[2 * e + 1] * 4.f;
    float lu = floorf(u), lv = floorf(v);
    float fu = u - lu, fv = v - lv;
    int iu = (int)lu;  iu = iu < 0 ? 0 : (iu > 4 ? 4 : iu);
    int iv = (int)lv;  iv = iv < 0 ? 0 : (iv > 4 ? 4 : iv);
    int iu1 = iu + 1 > 4 ? 4 : iu + 1;
    int iv1 = iv + 1 > 4 ? 4 : iv + 1;
    uint wp = (uint)(iu + 5 * iv) | ((uint)(iu + 5 * iv1) << 8) |
              ((uint)(iu1 + 5 * iv) << 16) | ((uint)(iu1 + 5 * iv1) << 24);
    int pos = atomicAdd(&cursor[dst], 1);
    esrc[pos] = src;
    ewi[pos] = wp;
    ebasis[pos] = make_float4((1.f - fu) * (1.f - fv), (1.f - fu) * fv,
                              fu * (1.f - fv), fu * fv);
}

// ---------------- MFMA GEMM: xW (26 tiles; tile 25 = root, fp32) --------
// A: [Npad][64] bf16. Wt: [26][o][i] bf16. Grid (26, Npad/64), 256 thr.
// bx<25: bf16 out to xWb [Npad][1600] via LDS-staged uint4 stores.
// bx==25: fp32 out to xRoot [Npad][64] direct.
// Fragment maps (m89/m91-verified):
//   A[m][k]: m=lane&15, k=(lane>>4)*8+j ; B[n][k] same ; C: col=l16, row=half*4+r
__global__ __launch_bounds__(256) void gemm_xw(
    const ushort* __restrict__ A, const ushort* __restrict__ Wt,
    ushort* __restrict__ xWb, float* __restrict__ xRoot)
{
    __shared__ ushort Cs[64][72];   // 144 B/row: uint4-aligned, bank-spread
    const int bx = blockIdx.x;
    const int wave = threadIdx.x >> 6;
    const int lane = threadIdx.x & 63;
    const int l16 = lane & 15;
    const int half = lane >> 4;                 // 0..3
    const int m0 = blockIdx.y * 64;
    const int m_base = m0 + wave * 16;

    const ushort* arow = A + (size_t)(m_base + l16) * 64;
    bf16x8 a0 = *(const bf16x8*)(arow + half * 8);
    bf16x8 a1 = *(const bf16x8*)(arow + 32 + half * 8);

    const ushort* btile = Wt + (size_t)bx * 4096;
    f32x4 acc[4];
    #pragma unroll
    for (int s = 0; s < 4; ++s) {
        acc[s] = (f32x4){0.f, 0.f, 0.f, 0.f};
        const ushort* brow = btile + (size_t)(s * 16 + l16) * 64;
        bf16x8 b0 = *(const bf16x8*)(brow + half * 8);
        bf16x8 b1 = *(const bf16x8*)(brow + 32 + half * 8);
        acc[s] = __builtin_amdgcn_mfma_f32_16x16x32_bf16(a0, b0, acc[s], 0, 0, 0);
        acc[s] = __builtin_amdgcn_mfma_f32_16x16x32_bf16(a1, b1, acc[s], 0, 0, 0);
    }

    if (bx == 25) {     // root tile -> fp32 xRoot (padded ws, no guard)
        #pragma unroll
        for (int s = 0; s < 4; ++s)
            #pragma unroll
            for (int r = 0; r < 4; ++r)
                xRoot[(size_t)(m_base + half * 4 + r) * 64 + s * 16 + l16] = acc[s][r];
        return;
    }

    // bf16 tile -> LDS
    #pragma unroll
    for (int s = 0; s < 4; ++s)
        #pragma unroll
        for (int r = 0; r < 4; ++r)
            Cs[wave * 16 + half * 4 + r][s * 16 + l16] = f2bf(acc[s][r]);
    __syncthreads();

    // coalesced store: 64 rows x 128 B; 512 uint4, 2 per thread
    const int tid = threadIdx.x;
    #pragma unroll
    for (int it = 0; it < 2; ++it) {
        int idx = tid + it * 256;
        int row = idx >> 3, seg = idx & 7;
        uint4 v = *(const uint4*)&Cs[row][seg * 8];
        *(uint4*)(xWb + (size_t)(m0 + row) * 1600 + bx * 64 + seg * 8) = v;
    }
}

// ---------------- edge pass: wave per dst, fused node epilogue ----------
__global__ __launch_bounds__(256) void edge_csr(
    const ushort* __restrict__ xWb, const int* __restrict__ row_ptr,
    const int* __restrict__ esrc, const uint* __restrict__ ewi,
    const float4* __restrict__ ebasis, const float* __restrict__ xRoot,
    const float* __restrict__ bias, float* __restrict__ outf,
    ushort* __restrict__ outb, int N)
{
    int d = blockIdx.x * 4 + (threadIdx.x >> 6);
    int lane = threadIdx.x & 63;
    if (d >= N) return;
    int e0 = row_ptr[d], e1 = row_ptr[d + 1];
    float vmax = -__builtin_inff();
    for (int e = e0; e < e1; ++e) {
        int src = esrc[e];
        uint wp = ewi[e];
        float4 b = ebasis[e];
        const ushort* row = xWb + (size_t)src * 1600;
        float m = b.x * bf2f(row[(wp & 31) * 64 + lane]);
        m = fmaf(b.y, bf2f(row[((wp >> 8) & 31) * 64 + lane]), m);
        m = fmaf(b.z, bf2f(row[((wp >> 16) & 31) * 64 + lane]), m);
        m = fmaf(b.w, bf2f(row[(wp >> 24) * 64 + lane]), m);
        vmax = fmaxf(vmax, m);
    }
    if (e1 == e0) vmax = 0.f;          // segment_max(-inf) -> 0
    float val = vmax + xRoot[(size_t)d * 64 + lane] + bias[lane];
    val = fmaxf(val, 0.f);
    outf[(size_t)d * 64 + lane] = val;
    if (outb) outb[(size_t)d * 64 + lane] = f2bf(val);
}

// ---------------- final: out = [x|x1|x2] @ fw + fb (fp32) ---------------
__global__ __launch_bounds__(256) void final_gemm(
    const float* __restrict__ x, const float* __restrict__ x1,
    const float* __restrict__ x2, const float* __restrict__ fw,
    const float* __restrict__ fb, float* __restrict__ out, int M)
{
    __shared__ float As[64][68];
    __shared__ float Bs[64][68];
    const int m0 = blockIdx.x * 64;
    const int tid = threadIdx.x;
    const int tx = tid & 15, ty = tid >> 4;
    float acc[4][4] = {};
    const float* srcs[3] = {x, x1, x2};

    for (int kt = 0; kt < 3; ++kt) {
        const float* A = srcs[kt];
        const float4* B4 = (const float4*)(fw + (size_t)kt * 4096);
        #pragma unroll
        for (int r = 0; r < 4; ++r) {
            int idx = tid + r * 256;
            float4 v = B4[idx];
            int i = idx >> 4;
            int o = (idx & 15) * 4;
            Bs[i][o] = v.x; Bs[i][o + 1] = v.y; Bs[i][o + 2] = v.z; Bs[i][o + 3] = v.w;
        }
        #pragma unroll
        for (int r = 0; r < 4; ++r) {
            int idx = tid + r * 256;
            int m = idx >> 4;
            int k = (idx & 15) * 4;
            int gm = m0 + m;
            float4 v = make_float4(0.f, 0.f, 0.f, 0.f);
            if (gm < M) v = *(const float4*)(A + (size_t)gm * 64 + k);
            As[k][m] = v.x; As[k + 1][m] = v.y; As[k + 2][m] = v.z; As[k + 3][m] = v.w;
        }
        __syncthreads();
        #pragma unroll 8
        for (int k = 0; k < 64; ++k) {
            float4 av = *(const float4*)&As[k][ty * 4];
            float4 bv = *(const float4*)&Bs[k][tx * 4];
            float aa[4] = {av.x, av.y, av.z, av.w};
            float bb[4] = {bv.x, bv.y, bv.z, bv.w};
            #pragma unroll
            for (int i = 0; i < 4; ++i)
                #pragma unroll
                for (int j = 0; j < 4; ++j)
                    acc[i][j] = fmaf(aa[i], bb[j], acc[i][j]);
        }
        __syncthreads();
    }

    #pragma unroll
    for (int i = 0; i < 4; ++i) {
        int gm = m0 + ty * 4 + i;
        if (gm < M) {
            float4 v = make_float4(acc[i][0] + fb[tx * 4 + 0],
                                   acc[i][1] + fb[tx * 4 + 1],
                                   acc[i][2] + fb[tx * 4 + 2],
                                   acc[i][3] + fb[tx * 4 + 3]);
            *(float4*)(out + (size_t)gm * 64 + tx * 4) = v;
        }
    }
}

extern "C" void kernel_launch(void* const* d_in, const int* in_sizes, int n_in,
                              void* d_out, int out_size, void* d_ws, size_t ws_size,
                              hipStream_t stream)
{
    const float* x    = (const float*)d_in[0];
    const int*   ei   = (const int*)d_in[1];
    const float* attr = (const float*)d_in[2];
    const float* W1   = (const float*)d_in[3];
    const float* r1   = (const float*)d_in[4];
    const float* b1   = (const float*)d_in[5];
    const float* W2   = (const float*)d_in[6];
    const float* r2   = (const float*)d_in[7];
    const float* b2   = (const float*)d_in[8];
    const float* fw   = (const float*)d_in[9];
    const float* fb   = (const float*)d_in[10];
    float* out = (float*)d_out;

    const int N = in_sizes[0] / 64;
    const int E = in_sizes[1] / 2;
    const int mtiles = (N + 63) / 64;
    const int Npad = mtiles * 64;

    // workspace carve (~220 MB; ws_size >= 358 MB per round-2 evidence)
    char* p = (char*)d_ws;
    auto alloc = [&](size_t bytes) { void* q = p; p += (bytes + 255) & ~(size_t)255; return q; };
    float4* ebasis = (float4*)alloc((size_t)E * 16);
    float*  x1f    = (float*)alloc((size_t)Npad * 64 * 4);
    float*  xRoot  = (float*)alloc((size_t)Npad * 64 * 4);
    ushort* xWb    = (ushort*)alloc((size_t)Npad * 1600 * 2);
    ushort* xb     = (ushort*)alloc((size_t)Npad * 64 * 2);
    ushort* x1b    = (ushort*)alloc((size_t)Npad * 64 * 2);
    ushort* WtA    = (ushort*)alloc((size_t)26 * 4096 * 2);
    ushort* WtB    = (ushort*)alloc((size_t)26 * 4096 * 2);
    int*    esrc   = (int*)alloc((size_t)E * 4);
    uint*   ewi    = (uint*)alloc((size_t)E * 4);
    int*    deg    = (int*)alloc((size_t)N * 4);
    int*    cursor = (int*)alloc((size_t)N * 4);
    int*    rowp   = (int*)alloc((size_t)(N + 1) * 4);
    int*    tmpinc = (int*)alloc((size_t)N * 4);
    int*    part   = (int*)alloc(64 * 4);

    const int nb = (N + 1023) / 1024;   // <= 64 for N <= 65536

    // converts (once per call)
    cvt_f32_bf16<<<(N * 64 + 255) / 256, 256, 0, stream>>>(x, xb, N * 64);
    cvt_WT<<<(26 * 4096 + 255) / 256, 256, 0, stream>>>(W1, r1, WtA);
    cvt_WT<<<(26 * 4096 + 255) / 256, 256, 0, stream>>>(W2, r2, WtB);

    // CSR build (once per call, reused by both layers)
    zero_ints<<<(N + 255) / 256, 256, 0, stream>>>(deg, N);
    hist_deg<<<(E + 255) / 256, 256, 0, stream>>>(ei, deg, E);
    scan_block<<<nb, 1024, 0, stream>>>(deg, tmpinc, part, N);
    scan_partial<<<1, 64, 0, stream>>>(part, nb);
    scan_finalize<<<nb, 1024, 0, stream>>>(deg, tmpinc, part, rowp, cursor, N);
    csr_scatter<<<(E + 255) / 256, 256, 0, stream>>>(ei, attr, cursor, esrc, ewi, ebasis, E);

    // layer 1
    gemm_xw<<<dim3(26, mtiles), 256, 0, stream>>>(xb, WtA, xWb, xRoot);
    edge_csr<<<(N + 3) / 4, 256, 0, stream>>>(xWb, rowp, esrc, ewi, ebasis, xRoot, b1, x1f, x1b, N);

    // layer 2 (x2 lives in d_out; final reads rows before writing them)
    gemm_xw<<<dim3(26, mtiles), 256, 0, stream>>>(x1b, WtB, xWb, xRoot);
    edge_csr<<<(N + 3) / 4, 256, 0, stream>>>(xWb, rowp, esrc, ewi, ebasis, xRoot, b2, out, nullptr, N);

    // final
    final_gemm<<<mtiles, 256, 0, stream>>>(x, x1f, out, fw, fb, out, N);
}

// Round 5
// 481.735 us; speedup vs baseline: 2.3070x; 1.1833x over previous
//
#include <hip/hip_runtime.h>
#include <hip/hip_bf16.h>

// SplineCNN round 5: de-latency the xW GEMM.
// Round-4 evidence: LDS-staged coalesced stores changed nothing (105->102us),
// VGPR_Count=32, MfmaUtil 4%, VALUBusy 11%, occ 82% => latency-bound, no
// per-wave ILP, 8 MFMAs per block. Now: B fragments held in registers once
// per wave; block covers 4 M-sub-tiles (grid 26 x mtiles/4) => 32 MFMAs per
// wave, B-load latency amortized 4x, loads of iter i+1 overlap stores of i.

typedef short  bf16x8 __attribute__((ext_vector_type(8)));
typedef float  f32x4  __attribute__((ext_vector_type(4)));

__device__ __forceinline__ float bf2f(ushort u) {
    return __uint_as_float((uint)u << 16);
}
__device__ __forceinline__ ushort f2bf(float f) {   // round-to-nearest-even
    uint u = __float_as_uint(f);
    return (ushort)((u + 0x7FFF + ((u >> 16) & 1)) >> 16);
}

// ---------------- converts ----------------------------------------------
__global__ __launch_bounds__(256) void cvt_f32_bf16(
    const float* __restrict__ in, ushort* __restrict__ out, int n)
{
    int i = blockIdx.x * 256 + threadIdx.x;
    if (i < n) out[i] = f2bf(in[i]);
}

// W[25][i][o] + root[i][o] (fp32) -> Wt[26][o][i] (bf16)
__global__ __launch_bounds__(256) void cvt_WT(
    const float* __restrict__ W, const float* __restrict__ root,
    ushort* __restrict__ Wt)
{
    int idx = blockIdx.x * 256 + threadIdx.x;
    if (idx >= 26 * 4096) return;
    int tile = idx >> 12, rem = idx & 4095, o = rem >> 6, i = rem & 63;
    float v = (tile < 25) ? W[tile * 4096 + i * 64 + o] : root[i * 64 + o];
    Wt[idx] = f2bf(v);
}

// ---------------- CSR build ---------------------------------------------
__global__ __launch_bounds__(256) void zero_ints(int* __restrict__ p, int n)
{
    int i = blockIdx.x * 256 + threadIdx.x;
    if (i < n) p[i] = 0;
}

__global__ __launch_bounds__(256) void hist_deg(
    const int* __restrict__ ei, int* __restrict__ deg, int E)
{
    int e = blockIdx.x * 256 + threadIdx.x;
    if (e < E) atomicAdd(&deg[ei[E + e]], 1);
}

__global__ __launch_bounds__(1024) void scan_block(
    const int* __restrict__ deg, int* __restrict__ inc,
    int* __restrict__ partial, int N)
{
    __shared__ int s[1024];
    int i = blockIdx.x * 1024 + threadIdx.x;
    int v = (i < N) ? deg[i] : 0;
    s[threadIdx.x] = v;
    __syncthreads();
    for (int off = 1; off < 1024; off <<= 1) {
        int t = (threadIdx.x >= off) ? s[threadIdx.x - off] : 0;
        __syncthreads();
        s[threadIdx.x] += t;
        __syncthreads();
    }
    if (i < N) inc[i] = s[threadIdx.x];
    if (threadIdx.x == 1023) partial[blockIdx.x] = s[1023];
}

__global__ void scan_partial(int* __restrict__ partial, int nb)  // nb <= 64
{
    __shared__ int s[64];
    int t = threadIdx.x;
    int v = (t < nb) ? partial[t] : 0;
    s[t] = v;
    __syncthreads();
    for (int off = 1; off < 64; off <<= 1) {
        int x = (t >= off) ? s[t - off] : 0;
        __syncthreads();
        s[t] += x;
        __syncthreads();
    }
    if (t < nb) partial[t] = s[t] - v;   // exclusive block offsets
}

__global__ __launch_bounds__(1024) void scan_finalize(
    const int* __restrict__ deg, const int* __restrict__ inc,
    const int* __restrict__ partial, int* __restrict__ row_ptr,
    int* __restrict__ cursor, int N)
{
    int i = blockIdx.x * 1024 + threadIdx.x;
    if (i >= N) return;
    int v = inc[i] + partial[blockIdx.x];
    row_ptr[i + 1] = v;
    cursor[i] = v - deg[i];
    if (i == 0) row_ptr[0] = 0;
}

// per-edge: compute spline basis/wi once (layer-independent), scatter into CSR
__global__ __launch_bounds__(256) void csr_scatter(
    const int* __restrict__ ei, const float* __restrict__ attr,
    int* __restrict__ cursor, int* __restrict__ esrc,
    uint* __restrict__ ewi, float4* __restrict__ ebasis, int E)
{
    int e = blockIdx.x * 256 + threadIdx.x;
    if (e >= E) return;
    int src = ei[e], dst = ei[E + e];
    float u = attr[2 * e] * 4.f;
    float v = attr[2 * e + 1] * 4.f;
    float lu = floorf(u), lv = floorf(v);
    float fu = u - lu, fv = v - lv;
    int iu = (int)lu;  iu = iu < 0 ? 0 : (iu > 4 ? 4 : iu);
    int iv = (int)lv;  iv = iv < 0 ? 0 : (iv > 4 ? 4 : iv);
    int iu1 = iu + 1 > 4 ? 4 : iu + 1;
    int iv1 = iv + 1 > 4 ? 4 : iv + 1;
    uint wp = (uint)(iu + 5 * iv) | ((uint)(iu + 5 * iv1) << 8) |
              ((uint)(iu1 + 5 * iv) << 16) | ((uint)(iu1 + 5 * iv1) << 24);
    int pos = atomicAdd(&cursor[dst], 1);
    esrc[pos] = src;
    ewi[pos] = wp;
    ebasis[pos] = make_float4((1.f - fu) * (1.f - fv), (1.f - fu) * fv,
                              fu * (1.f - fv), fu * fv);
}

// ---------------- MFMA GEMM: xW (26 tiles; tile 25 = root, fp32) --------
// A: [Npad][64] bf16. Wt: [26][o][i] bf16. Grid (26, ceil(mtiles/4)), 256 thr.
// Per wave: B fragments (8) live in registers for the whole block; loop 4
// M-sub-tiles of 64 rows: {2 A-frag loads, 8 MFMAs, LDS stage, uint4 store}.
// Fragment maps (m89/m91-verified):
//   A[m][k]: m=lane&15, k=(lane>>4)*8+j ; B[n][k] same ; C: col=l16, row=half*4+r
__global__ __launch_bounds__(256) void gemm_xw(
    const ushort* __restrict__ A, const ushort* __restrict__ Wt,
    ushort* __restrict__ xWb, float* __restrict__ xRoot, int mtiles)
{
    __shared__ ushort Cs[64][72];   // 144 B/row: uint4-aligned, bank-spread
    const int bx = blockIdx.x;
    const int wave = threadIdx.x >> 6;
    const int lane = threadIdx.x & 63;
    const int l16 = lane & 15;
    const int half = lane >> 4;                 // 0..3
    const int tid = threadIdx.x;

    // B fragments once per wave (~32 VGPRs: this is deliberate — ILP)
    const ushort* btile = Wt + (size_t)bx * 4096;
    bf16x8 b0[4], b1[4];
    #pragma unroll
    for (int s = 0; s < 4; ++s) {
        const ushort* brow = btile + (size_t)(s * 16 + l16) * 64;
        b0[s] = *(const bf16x8*)(brow + half * 8);
        b1[s] = *(const bf16x8*)(brow + 32 + half * 8);
    }

    for (int it = 0; it < 4; ++it) {
        const int mt = blockIdx.y * 4 + it;
        if (mt >= mtiles) break;                 // block-uniform
        const int m0 = mt * 64;
        const int m_base = m0 + wave * 16;

        const ushort* arow = A + (size_t)(m_base + l16) * 64;
        bf16x8 a0 = *(const bf16x8*)(arow + half * 8);
        bf16x8 a1 = *(const bf16x8*)(arow + 32 + half * 8);

        f32x4 acc[4];
        #pragma unroll
        for (int s = 0; s < 4; ++s) {
            acc[s] = (f32x4){0.f, 0.f, 0.f, 0.f};
            acc[s] = __builtin_amdgcn_mfma_f32_16x16x32_bf16(a0, b0[s], acc[s], 0, 0, 0);
            acc[s] = __builtin_amdgcn_mfma_f32_16x16x32_bf16(a1, b1[s], acc[s], 0, 0, 0);
        }

        if (bx == 25) {   // root tile -> fp32 xRoot (padded ws, no guard)
            #pragma unroll
            for (int s = 0; s < 4; ++s)
                #pragma unroll
                for (int r = 0; r < 4; ++r)
                    xRoot[(size_t)(m_base + half * 4 + r) * 64 + s * 16 + l16] = acc[s][r];
            continue;
        }

        // bf16 tile -> LDS -> coalesced uint4 store
        #pragma unroll
        for (int s = 0; s < 4; ++s)
            #pragma unroll
            for (int r = 0; r < 4; ++r)
                Cs[wave * 16 + half * 4 + r][s * 16 + l16] = f2bf(acc[s][r]);
        __syncthreads();
        #pragma unroll
        for (int i2 = 0; i2 < 2; ++i2) {
            int idx = tid + i2 * 256;
            int row = idx >> 3, seg = idx & 7;
            uint4 v = *(const uint4*)&Cs[row][seg * 8];
            *(uint4*)(xWb + (size_t)(m0 + row) * 1600 + bx * 64 + seg * 8) = v;
        }
        __syncthreads();   // protect Cs against next iteration's writes
    }
}

// ---------------- edge pass: wave per dst, fused node epilogue ----------
__global__ __launch_bounds__(256) void edge_csr(
    const ushort* __restrict__ xWb, const int* __restrict__ row_ptr,
    const int* __restrict__ esrc, const uint* __restrict__ ewi,
    const float4* __restrict__ ebasis, const float* __restrict__ xRoot,
    const float* __restrict__ bias, float* __restrict__ outf,
    ushort* __restrict__ outb, int N)
{
    int d = blockIdx.x * 4 + (threadIdx.x >> 6);
    int lane = threadIdx.x & 63;
    if (d >= N) return;
    int e0 = row_ptr[d], e1 = row_ptr[d + 1];
    float vmax = -__builtin_inff();
    for (int e = e0; e < e1; ++e) {
        int src = esrc[e];
        uint wp = ewi[e];
        float4 b = ebasis[e];
        const ushort* row = xWb + (size_t)src * 1600;
        float m = b.x * bf2f(row[(wp & 31) * 64 + lane]);
        m = fmaf(b.y, bf2f(row[((wp >> 8) & 31) * 64 + lane]), m);
        m = fmaf(b.z, bf2f(row[((wp >> 16) & 31) * 64 + lane]), m);
        m = fmaf(b.w, bf2f(row[(wp >> 24) * 64 + lane]), m);
        vmax = fmaxf(vmax, m);
    }
    if (e1 == e0) vmax = 0.f;          // segment_max(-inf) -> 0
    float val = vmax + xRoot[(size_t)d * 64 + lane] + bias[lane];
    val = fmaxf(val, 0.f);
    outf[(size_t)d * 64 + lane] = val;
    if (outb) outb[(size_t)d * 64 + lane] = f2bf(val);
}

// ---------------- final: out = [x|x1|x2] @ fw + fb (fp32) ---------------
__global__ __launch_bounds__(256) void final_gemm(
    const float* __restrict__ x, const float* __restrict__ x1,
    const float* __restrict__ x2, const float* __restrict__ fw,
    const float* __restrict__ fb, float* __restrict__ out, int M)
{
    __shared__ float As[64][68];
    __shared__ float Bs[64][68];
    const int m0 = blockIdx.x * 64;
    const int tid = threadIdx.x;
    const int tx = tid & 15, ty = tid >> 4;
    float acc[4][4] = {};
    const float* srcs[3] = {x, x1, x2};

    for (int kt = 0; kt < 3; ++kt) {
        const float* A = srcs[kt];
        const float4* B4 = (const float4*)(fw + (size_t)kt * 4096);
        #pragma unroll
        for (int r = 0; r < 4; ++r) {
            int idx = tid + r * 256;
            float4 v = B4[idx];
            int i = idx >> 4;
            int o = (idx & 15) * 4;
            Bs[i][o] = v.x; Bs[i][o + 1] = v.y; Bs[i][o + 2] = v.z; Bs[i][o + 3] = v.w;
        }
        #pragma unroll
        for (int r = 0; r < 4; ++r) {
            int idx = tid + r * 256;
            int m = idx >> 4;
            int k = (idx & 15) * 4;
            int gm = m0 + m;
            float4 v = make_float4(0.f, 0.f, 0.f, 0.f);
            if (gm < M) v = *(const float4*)(A + (size_t)gm * 64 + k);
            As[k][m] = v.x; As[k + 1][m] = v.y; As[k + 2][m] = v.z; As[k + 3][m] = v.w;
        }
        __syncthreads();
        #pragma unroll 8
        for (int k = 0; k < 64; ++k) {
            float4 av = *(const float4*)&As[k][ty * 4];
            float4 bv = *(const float4*)&Bs[k][tx * 4];
            float aa[4] = {av.x, av.y, av.z, av.w};
            float bb[4] = {bv.x, bv.y, bv.z, bv.w};
            #pragma unroll
            for (int i = 0; i < 4; ++i)
                #pragma unroll
                for (int j = 0; j < 4; ++j)
                    acc[i][j] = fmaf(aa[i], bb[j], acc[i][j]);
        }
        __syncthreads();
    }

    #pragma unroll
    for (int i = 0; i < 4; ++i) {
        int gm = m0 + ty * 4 + i;
        if (gm < M) {
            float4 v = make_float4(acc[i][0] + fb[tx * 4 + 0],
                                   acc[i][1] + fb[tx * 4 + 1],
                                   acc[i][2] + fb[tx * 4 + 2],
                                   acc[i][3] + fb[tx * 4 + 3]);
            *(float4*)(out + (size_t)gm * 64 + tx * 4) = v;
        }
    }
}

extern "C" void kernel_launch(void* const* d_in, const int* in_sizes, int n_in,
                              void* d_out, int out_size, void* d_ws, size_t ws_size,
                              hipStream_t stream)
{
    const float* x    = (const float*)d_in[0];
    const int*   ei   = (const int*)d_in[1];
    const float* attr = (const float*)d_in[2];
    const float* W1   = (const float*)d_in[3];
    const float* r1   = (const float*)d_in[4];
    const float* b1   = (const float*)d_in[5];
    const float* W2   = (const float*)d_in[6];
    const float* r2   = (const float*)d_in[7];
    const float* b2   = (const float*)d_in[8];
    const float* fw   = (const float*)d_in[9];
    const float* fb   = (const float*)d_in[10];
    float* out = (float*)d_out;

    const int N = in_sizes[0] / 64;
    const int E = in_sizes[1] / 2;
    const int mtiles = (N + 63) / 64;
    const int Npad = mtiles * 64;

    // workspace carve (~220 MB; ws_size >= 358 MB per round-2 evidence)
    char* p = (char*)d_ws;
    auto alloc = [&](size_t bytes) { void* q = p; p += (bytes + 255) & ~(size_t)255; return q; };
    float4* ebasis = (float4*)alloc((size_t)E * 16);
    float*  x1f    = (float*)alloc((size_t)Npad * 64 * 4);
    float*  xRoot  = (float*)alloc((size_t)Npad * 64 * 4);
    ushort* xWb    = (ushort*)alloc((size_t)Npad * 1600 * 2);
    ushort* xb     = (ushort*)alloc((size_t)Npad * 64 * 2);
    ushort* x1b    = (ushort*)alloc((size_t)Npad * 64 * 2);
    ushort* WtA    = (ushort*)alloc((size_t)26 * 4096 * 2);
    ushort* WtB    = (ushort*)alloc((size_t)26 * 4096 * 2);
    int*    esrc   = (int*)alloc((size_t)E * 4);
    uint*   ewi    = (uint*)alloc((size_t)E * 4);
    int*    deg    = (int*)alloc((size_t)N * 4);
    int*    cursor = (int*)alloc((size_t)N * 4);
    int*    rowp   = (int*)alloc((size_t)(N + 1) * 4);
    int*    tmpinc = (int*)alloc((size_t)N * 4);
    int*    part   = (int*)alloc(64 * 4);

    const int nb = (N + 1023) / 1024;   // <= 64 for N <= 65536

    // converts (once per call)
    cvt_f32_bf16<<<(N * 64 + 255) / 256, 256, 0, stream>>>(x, xb, N * 64);
    cvt_WT<<<(26 * 4096 + 255) / 256, 256, 0, stream>>>(W1, r1, WtA);
    cvt_WT<<<(26 * 4096 + 255) / 256, 256, 0, stream>>>(W2, r2, WtB);

    // CSR build (once per call, reused by both layers)
    zero_ints<<<(N + 255) / 256, 256, 0, stream>>>(deg, N);
    hist_deg<<<(E + 255) / 256, 256, 0, stream>>>(ei, deg, E);
    scan_block<<<nb, 1024, 0, stream>>>(deg, tmpinc, part, N);
    scan_partial<<<1, 64, 0, stream>>>(part, nb);
    scan_finalize<<<nb, 1024, 0, stream>>>(deg, tmpinc, part, rowp, cursor, N);
    csr_scatter<<<(E + 255) / 256, 256, 0, stream>>>(ei, attr, cursor, esrc, ewi, ebasis, E);

    const dim3 ggrid(26, (mtiles + 3) / 4);

    // layer 1
    gemm_xw<<<ggrid, 256, 0, stream>>>(xb, WtA, xWb, xRoot, mtiles);
    edge_csr<<<(N + 3) / 4, 256, 0, stream>>>(xWb, rowp, esrc, ewi, ebasis, xRoot, b1, x1f, x1b, N);

    // layer 2 (x2 lives in d_out; final reads rows before writing them)
    gemm_xw<<<ggrid, 256, 0, stream>>>(x1b, WtB, xWb, xRoot, mtiles);
    edge_csr<<<(N + 3) / 4, 256, 0, stream>>>(xWb, rowp, esrc, ewi, ebasis, xRoot, b2, out, nullptr, N);

    // final
    final_gemm<<<mtiles, 256, 0, stream>>>(x, x1f, out, fw, fb, out, N);
}

// Round 6
// 460.822 us; speedup vs baseline: 2.4117x; 1.0454x over previous
//
#include <hip/hip_runtime.h>
#include <hip/hip_bf16.h>

// SplineCNN round 6: de-VALU the edge pass.
// Round-5 evidence: edge_csr 88.7us x2, FETCH 215MB (~ideal), VALUBusy 67%
// => VALU-bound on per-edge address math (memory floor ~34us). Now:
// csr_scatter precomputes int4 byte-offsets (src*3200 + wi*128, layer-
// invariant); edge loop = per-lane base ptr + 4x{add,load,shift,fma};
// 2-edge unroll for MLP.

typedef short  bf16x8 __attribute__((ext_vector_type(8)));
typedef float  f32x4  __attribute__((ext_vector_type(4)));

__device__ __forceinline__ float bf2f(ushort u) {
    return __uint_as_float((uint)u << 16);
}
__device__ __forceinline__ ushort f2bf(float f) {   // round-to-nearest-even
    uint u = __float_as_uint(f);
    return (ushort)((u + 0x7FFF + ((u >> 16) & 1)) >> 16);
}

// ---------------- converts ----------------------------------------------
__global__ __launch_bounds__(256) void cvt_f32_bf16(
    const float* __restrict__ in, ushort* __restrict__ out, int n)
{
    int i = blockIdx.x * 256 + threadIdx.x;
    if (i < n) out[i] = f2bf(in[i]);
}

// W[25][i][o] + root[i][o] (fp32) -> Wt[26][o][i] (bf16)
__global__ __launch_bounds__(256) void cvt_WT(
    const float* __restrict__ W, const float* __restrict__ root,
    ushort* __restrict__ Wt)
{
    int idx = blockIdx.x * 256 + threadIdx.x;
    if (idx >= 26 * 4096) return;
    int tile = idx >> 12, rem = idx & 4095, o = rem >> 6, i = rem & 63;
    float v = (tile < 25) ? W[tile * 4096 + i * 64 + o] : root[i * 64 + o];
    Wt[idx] = f2bf(v);
}

// ---------------- CSR build ---------------------------------------------
__global__ __launch_bounds__(256) void zero_ints(int* __restrict__ p, int n)
{
    int i = blockIdx.x * 256 + threadIdx.x;
    if (i < n) p[i] = 0;
}

__global__ __launch_bounds__(256) void hist_deg(
    const int* __restrict__ ei, int* __restrict__ deg, int E)
{
    int e = blockIdx.x * 256 + threadIdx.x;
    if (e < E) atomicAdd(&deg[ei[E + e]], 1);
}

__global__ __launch_bounds__(1024) void scan_block(
    const int* __restrict__ deg, int* __restrict__ inc,
    int* __restrict__ partial, int N)
{
    __shared__ int s[1024];
    int i = blockIdx.x * 1024 + threadIdx.x;
    int v = (i < N) ? deg[i] : 0;
    s[threadIdx.x] = v;
    __syncthreads();
    for (int off = 1; off < 1024; off <<= 1) {
        int t = (threadIdx.x >= off) ? s[threadIdx.x - off] : 0;
        __syncthreads();
        s[threadIdx.x] += t;
        __syncthreads();
    }
    if (i < N) inc[i] = s[threadIdx.x];
    if (threadIdx.x == 1023) partial[blockIdx.x] = s[1023];
}

__global__ void scan_partial(int* __restrict__ partial, int nb)  // nb <= 64
{
    __shared__ int s[64];
    int t = threadIdx.x;
    int v = (t < nb) ? partial[t] : 0;
    s[t] = v;
    __syncthreads();
    for (int off = 1; off < 64; off <<= 1) {
        int x = (t >= off) ? s[t - off] : 0;
        __syncthreads();
        s[t] += x;
        __syncthreads();
    }
    if (t < nb) partial[t] = s[t] - v;   // exclusive block offsets
}

__global__ __launch_bounds__(1024) void scan_finalize(
    const int* __restrict__ deg, const int* __restrict__ inc,
    const int* __restrict__ partial, int* __restrict__ row_ptr,
    int* __restrict__ cursor, int N)
{
    int i = blockIdx.x * 1024 + threadIdx.x;
    if (i >= N) return;
    int v = inc[i] + partial[blockIdx.x];
    row_ptr[i + 1] = v;
    cursor[i] = v - deg[i];
    if (i == 0) row_ptr[0] = 0;
}

// per-edge: spline basis + precomputed gather byte-offsets (layer-invariant)
__global__ __launch_bounds__(256) void csr_scatter(
    const int* __restrict__ ei, const float* __restrict__ attr,
    int* __restrict__ cursor, int4* __restrict__ eoffs,
    float4* __restrict__ ebasis, int E)
{
    int e = blockIdx.x * 256 + threadIdx.x;
    if (e >= E) return;
    int src = ei[e], dst = ei[E + e];
    float u = attr[2 * e] * 4.f;
    float v = attr[2 * e + 1] * 4.f;
    float lu = floorf(u), lv = floorf(v);
    float fu = u - lu, fv = v - lv;
    int iu = (int)lu;  iu = iu < 0 ? 0 : (iu > 4 ? 4 : iu);
    int iv = (int)lv;  iv = iv < 0 ? 0 : (iv > 4 ? 4 : iv);
    int iu1 = iu + 1 > 4 ? 4 : iu + 1;
    int iv1 = iv + 1 > 4 ? 4 : iv + 1;
    int rb = src * 3200;                       // byte offset of row (1600 bf16)
    int pos = atomicAdd(&cursor[dst], 1);
    eoffs[pos] = make_int4(rb + (iu + 5 * iv) * 128, rb + (iu + 5 * iv1) * 128,
                           rb + (iu1 + 5 * iv) * 128, rb + (iu1 + 5 * iv1) * 128);
    ebasis[pos] = make_float4((1.f - fu) * (1.f - fv), (1.f - fu) * fv,
                              fu * (1.f - fv), fu * fv);
}

// ---------------- MFMA GEMM: xW (26 tiles; tile 25 = root, fp32) --------
__global__ __launch_bounds__(256) void gemm_xw(
    const ushort* __restrict__ A, const ushort* __restrict__ Wt,
    ushort* __restrict__ xWb, float* __restrict__ xRoot, int mtiles)
{
    __shared__ ushort Cs[64][72];   // 144 B/row: uint4-aligned, bank-spread
    const int bx = blockIdx.x;
    const int wave = threadIdx.x >> 6;
    const int lane = threadIdx.x & 63;
    const int l16 = lane & 15;
    const int half = lane >> 4;                 // 0..3
    const int tid = threadIdx.x;

    // B fragments once per wave (~32 VGPRs: deliberate — ILP)
    const ushort* btile = Wt + (size_t)bx * 4096;
    bf16x8 b0[4], b1[4];
    #pragma unroll
    for (int s = 0; s < 4; ++s) {
        const ushort* brow = btile + (size_t)(s * 16 + l16) * 64;
        b0[s] = *(const bf16x8*)(brow + half * 8);
        b1[s] = *(const bf16x8*)(brow + 32 + half * 8);
    }

    for (int it = 0; it < 4; ++it) {
        const int mt = blockIdx.y * 4 + it;
        if (mt >= mtiles) break;                 // block-uniform
        const int m0 = mt * 64;
        const int m_base = m0 + wave * 16;

        const ushort* arow = A + (size_t)(m_base + l16) * 64;
        bf16x8 a0 = *(const bf16x8*)(arow + half * 8);
        bf16x8 a1 = *(const bf16x8*)(arow + 32 + half * 8);

        f32x4 acc[4];
        #pragma unroll
        for (int s = 0; s < 4; ++s) {
            acc[s] = (f32x4){0.f, 0.f, 0.f, 0.f};
            acc[s] = __builtin_amdgcn_mfma_f32_16x16x32_bf16(a0, b0[s], acc[s], 0, 0, 0);
            acc[s] = __builtin_amdgcn_mfma_f32_16x16x32_bf16(a1, b1[s], acc[s], 0, 0, 0);
        }

        if (bx == 25) {   // root tile -> fp32 xRoot (padded ws, no guard)
            #pragma unroll
            for (int s = 0; s < 4; ++s)
                #pragma unroll
                for (int r = 0; r < 4; ++r)
                    xRoot[(size_t)(m_base + half * 4 + r) * 64 + s * 16 + l16] = acc[s][r];
            continue;
        }

        // bf16 tile -> LDS -> coalesced uint4 store
        #pragma unroll
        for (int s = 0; s < 4; ++s)
            #pragma unroll
            for (int r = 0; r < 4; ++r)
                Cs[wave * 16 + half * 4 + r][s * 16 + l16] = f2bf(acc[s][r]);
        __syncthreads();
        #pragma unroll
        for (int i2 = 0; i2 < 2; ++i2) {
            int idx = tid + i2 * 256;
            int row = idx >> 3, seg = idx & 7;
            uint4 v = *(const uint4*)&Cs[row][seg * 8];
            *(uint4*)(xWb + (size_t)(m0 + row) * 1600 + bx * 64 + seg * 8) = v;
        }
        __syncthreads();   // protect Cs against next iteration's writes
    }
}

// ---------------- edge pass: wave per dst, fused node epilogue ----------
// Precomputed byte-offsets; per-lane base pointer; 2-edge unroll for MLP.
__global__ __launch_bounds__(256) void edge_csr(
    const ushort* __restrict__ xWb, const int* __restrict__ row_ptr,
    const int4* __restrict__ eoffs, const float4* __restrict__ ebasis,
    const float* __restrict__ xRoot, const float* __restrict__ bias,
    float* __restrict__ outf, ushort* __restrict__ outb, int N)
{
    int d = blockIdx.x * 4 + (threadIdx.x >> 6);
    int lane = threadIdx.x & 63;
    if (d >= N) return;
    int e0 = row_ptr[d], e1 = row_ptr[d + 1];
    const char* base = (const char*)xWb + lane * 2;
    float vmax = -__builtin_inff();
    int e = e0;
    for (; e + 2 <= e1; e += 2) {
        int4 oa = eoffs[e];
        int4 ob = eoffs[e + 1];
        float4 ba = ebasis[e];
        float4 bb = ebasis[e + 1];
        float m0 = ba.x * bf2f(*(const ushort*)(base + oa.x));
        float m1 = bb.x * bf2f(*(const ushort*)(base + ob.x));
        m0 = fmaf(ba.y, bf2f(*(const ushort*)(base + oa.y)), m0);
        m1 = fmaf(bb.y, bf2f(*(const ushort*)(base + ob.y)), m1);
        m0 = fmaf(ba.z, bf2f(*(const ushort*)(base + oa.z)), m0);
        m1 = fmaf(bb.z, bf2f(*(const ushort*)(base + ob.z)), m1);
        m0 = fmaf(ba.w, bf2f(*(const ushort*)(base + oa.w)), m0);
        m1 = fmaf(bb.w, bf2f(*(const ushort*)(base + ob.w)), m1);
        vmax = fmaxf(vmax, fmaxf(m0, m1));
    }
    if (e < e1) {
        int4 oa = eoffs[e];
        float4 ba = ebasis[e];
        float m0 = ba.x * bf2f(*(const ushort*)(base + oa.x));
        m0 = fmaf(ba.y, bf2f(*(const ushort*)(base + oa.y)), m0);
        m0 = fmaf(ba.z, bf2f(*(const ushort*)(base + oa.z)), m0);
        m0 = fmaf(ba.w, bf2f(*(const ushort*)(base + oa.w)), m0);
        vmax = fmaxf(vmax, m0);
    }
    if (e1 == e0) vmax = 0.f;          // segment_max(-inf) -> 0
    float val = vmax + xRoot[(size_t)d * 64 + lane] + bias[lane];
    val = fmaxf(val, 0.f);
    outf[(size_t)d * 64 + lane] = val;
    if (outb) outb[(size_t)d * 64 + lane] = f2bf(val);
}

// ---------------- final: out = [x|x1|x2] @ fw + fb (fp32) ---------------
__global__ __launch_bounds__(256) void final_gemm(
    const float* __restrict__ x, const float* __restrict__ x1,
    const float* __restrict__ x2, const float* __restrict__ fw,
    const float* __restrict__ fb, float* __restrict__ out, int M)
{
    __shared__ float As[64][68];
    __shared__ float Bs[64][68];
    const int m0 = blockIdx.x * 64;
    const int tid = threadIdx.x;
    const int tx = tid & 15, ty = tid >> 4;
    float acc[4][4] = {};
    const float* srcs[3] = {x, x1, x2};

    for (int kt = 0; kt < 3; ++kt) {
        const float* A = srcs[kt];
        const float4* B4 = (const float4*)(fw + (size_t)kt * 4096);
        #pragma unroll
        for (int r = 0; r < 4; ++r) {
            int idx = tid + r * 256;
            float4 v = B4[idx];
            int i = idx >> 4;
            int o = (idx & 15) * 4;
            Bs[i][o] = v.x; Bs[i][o + 1] = v.y; Bs[i][o + 2] = v.z; Bs[i][o + 3] = v.w;
        }
        #pragma unroll
        for (int r = 0; r < 4; ++r) {
            int idx = tid + r * 256;
            int m = idx >> 4;
            int k = (idx & 15) * 4;
            int gm = m0 + m;
            float4 v = make_float4(0.f, 0.f, 0.f, 0.f);
            if (gm < M) v = *(const float4*)(A + (size_t)gm * 64 + k);
            As[k][m] = v.x; As[k + 1][m] = v.y; As[k + 2][m] = v.z; As[k + 3][m] = v.w;
        }
        __syncthreads();
        #pragma unroll 8
        for (int k = 0; k < 64; ++k) {
            float4 av = *(const float4*)&As[k][ty * 4];
            float4 bv = *(const float4*)&Bs[k][tx * 4];
            float aa[4] = {av.x, av.y, av.z, av.w};
            float bb[4] = {bv.x, bv.y, bv.z, bv.w};
            #pragma unroll
            for (int i = 0; i < 4; ++i)
                #pragma unroll
                for (int j = 0; j < 4; ++j)
                    acc[i][j] = fmaf(aa[i], bb[j], acc[i][j]);
        }
        __syncthreads();
    }

    #pragma unroll
    for (int i = 0; i < 4; ++i) {
        int gm = m0 + ty * 4 + i;
        if (gm < M) {
            float4 v = make_float4(acc[i][0] + fb[tx * 4 + 0],
                                   acc[i][1] + fb[tx * 4 + 1],
                                   acc[i][2] + fb[tx * 4 + 2],
                                   acc[i][3] + fb[tx * 4 + 3]);
            *(float4*)(out + (size_t)gm * 64 + tx * 4) = v;
        }
    }
}

extern "C" void kernel_launch(void* const* d_in, const int* in_sizes, int n_in,
                              void* d_out, int out_size, void* d_ws, size_t ws_size,
                              hipStream_t stream)
{
    const float* x    = (const float*)d_in[0];
    const int*   ei   = (const int*)d_in[1];
    const float* attr = (const float*)d_in[2];
    const float* W1   = (const float*)d_in[3];
    const float* r1   = (const float*)d_in[4];
    const float* b1   = (const float*)d_in[5];
    const float* W2   = (const float*)d_in[6];
    const float* r2   = (const float*)d_in[7];
    const float* b2   = (const float*)d_in[8];
    const float* fw   = (const float*)d_in[9];
    const float* fb   = (const float*)d_in[10];
    float* out = (float*)d_out;

    const int N = in_sizes[0] / 64;
    const int E = in_sizes[1] / 2;
    const int mtiles = (N + 63) / 64;
    const int Npad = mtiles * 64;

    // workspace carve (~220 MB; ws_size >= 358 MB per round-2 evidence)
    char* p = (char*)d_ws;
    auto alloc = [&](size_t bytes) { void* q = p; p += (bytes + 255) & ~(size_t)255; return q; };
    float4* ebasis = (float4*)alloc((size_t)E * 16);
    int4*   eoffs  = (int4*)alloc((size_t)E * 16);
    float*  x1f    = (float*)alloc((size_t)Npad * 64 * 4);
    float*  xRoot  = (float*)alloc((size_t)Npad * 64 * 4);
    ushort* xWb    = (ushort*)alloc((size_t)Npad * 1600 * 2);
    ushort* xb     = (ushort*)alloc((size_t)Npad * 64 * 2);
    ushort* x1b    = (ushort*)alloc((size_t)Npad * 64 * 2);
    ushort* WtA    = (ushort*)alloc((size_t)26 * 4096 * 2);
    ushort* WtB    = (ushort*)alloc((size_t)26 * 4096 * 2);
    int*    deg    = (int*)alloc((size_t)N * 4);
    int*    cursor = (int*)alloc((size_t)N * 4);
    int*    rowp   = (int*)alloc((size_t)(N + 1) * 4);
    int*    tmpinc = (int*)alloc((size_t)N * 4);
    int*    part   = (int*)alloc(64 * 4);

    const int nb = (N + 1023) / 1024;   // <= 64 for N <= 65536

    // converts (once per call)
    cvt_f32_bf16<<<(N * 64 + 255) / 256, 256, 0, stream>>>(x, xb, N * 64);
    cvt_WT<<<(26 * 4096 + 255) / 256, 256, 0, stream>>>(W1, r1, WtA);
    cvt_WT<<<(26 * 4096 + 255) / 256, 256, 0, stream>>>(W2, r2, WtB);

    // CSR build (once per call, reused by both layers)
    zero_ints<<<(N + 255) / 256, 256, 0, stream>>>(deg, N);
    hist_deg<<<(E + 255) / 256, 256, 0, stream>>>(ei, deg, E);
    scan_block<<<nb, 1024, 0, stream>>>(deg, tmpinc, part, N);
    scan_partial<<<1, 64, 0, stream>>>(part, nb);
    scan_finalize<<<nb, 1024, 0, stream>>>(deg, tmpinc, part, rowp, cursor, N);
    csr_scatter<<<(E + 255) / 256, 256, 0, stream>>>(ei, attr, cursor, eoffs, ebasis, E);

    const dim3 ggrid(26, (mtiles + 3) / 4);

    // layer 1
    gemm_xw<<<ggrid, 256, 0, stream>>>(xb, WtA, xWb, xRoot, mtiles);
    edge_csr<<<(N + 3) / 4, 256, 0, stream>>>(xWb, rowp, eoffs, ebasis, xRoot, b1, x1f, x1b, N);

    // layer 2 (x2 lives in d_out; final reads rows before writing them)
    gemm_xw<<<ggrid, 256, 0, stream>>>(x1b, WtB, xWb, xRoot, mtiles);
    edge_csr<<<(N + 3) / 4, 256, 0, stream>>>(xWb, rowp, eoffs, ebasis, xRoot, b2, out, nullptr, N);

    // final
    final_gemm<<<mtiles, 256, 0, stream>>>(x, x1f, out, fw, fb, out, N);
}

// Round 7
// 446.652 us; speedup vs baseline: 2.4883x; 1.0317x over previous
//
#include <hip/hip_runtime.h>
#include <hip/hip_bf16.h>

// SplineCNN round 7: scalarize the wave-uniform edge stream.
// Round-6 evidence: edge_csr 82.6us, VALUBusy 50%, mem floor ~34us. Root
// cause: d = bx*4 + (tid>>6) is not provably wave-uniform, so e0/e1, the
// eoffs/ebasis loads and all gather address math compile as VECTOR ops.
// Fix: readfirstlane the wave id (+ e0/e1) => s_load for per-edge data,
// SGPR-base + lane*2 addressing for gathers; VALU/edge ~25 -> ~10.

typedef short  bf16x8 __attribute__((ext_vector_type(8)));
typedef float  f32x4  __attribute__((ext_vector_type(4)));

__device__ __forceinline__ float bf2f(ushort u) {
    return __uint_as_float((uint)u << 16);
}
__device__ __forceinline__ ushort f2bf(float f) {   // round-to-nearest-even
    uint u = __float_as_uint(f);
    return (ushort)((u + 0x7FFF + ((u >> 16) & 1)) >> 16);
}

// ---------------- converts ----------------------------------------------
__global__ __launch_bounds__(256) void cvt_f32_bf16(
    const float* __restrict__ in, ushort* __restrict__ out, int n)
{
    int i = blockIdx.x * 256 + threadIdx.x;
    if (i < n) out[i] = f2bf(in[i]);
}

// W[25][i][o] + root[i][o] (fp32) -> Wt[26][o][i] (bf16)
__global__ __launch_bounds__(256) void cvt_WT(
    const float* __restrict__ W, const float* __restrict__ root,
    ushort* __restrict__ Wt)
{
    int idx = blockIdx.x * 256 + threadIdx.x;
    if (idx >= 26 * 4096) return;
    int tile = idx >> 12, rem = idx & 4095, o = rem >> 6, i = rem & 63;
    float v = (tile < 25) ? W[tile * 4096 + i * 64 + o] : root[i * 64 + o];
    Wt[idx] = f2bf(v);
}

// ---------------- CSR build ---------------------------------------------
__global__ __launch_bounds__(256) void zero_ints(int* __restrict__ p, int n)
{
    int i = blockIdx.x * 256 + threadIdx.x;
    if (i < n) p[i] = 0;
}

__global__ __launch_bounds__(256) void hist_deg(
    const int* __restrict__ ei, int* __restrict__ deg, int E)
{
    int e = blockIdx.x * 256 + threadIdx.x;
    if (e < E) atomicAdd(&deg[ei[E + e]], 1);
}

__global__ __launch_bounds__(1024) void scan_block(
    const int* __restrict__ deg, int* __restrict__ inc,
    int* __restrict__ partial, int N)
{
    __shared__ int s[1024];
    int i = blockIdx.x * 1024 + threadIdx.x;
    int v = (i < N) ? deg[i] : 0;
    s[threadIdx.x] = v;
    __syncthreads();
    for (int off = 1; off < 1024; off <<= 1) {
        int t = (threadIdx.x >= off) ? s[threadIdx.x - off] : 0;
        __syncthreads();
        s[threadIdx.x] += t;
        __syncthreads();
    }
    if (i < N) inc[i] = s[threadIdx.x];
    if (threadIdx.x == 1023) partial[blockIdx.x] = s[1023];
}

__global__ void scan_partial(int* __restrict__ partial, int nb)  // nb <= 64
{
    __shared__ int s[64];
    int t = threadIdx.x;
    int v = (t < nb) ? partial[t] : 0;
    s[t] = v;
    __syncthreads();
    for (int off = 1; off < 64; off <<= 1) {
        int x = (t >= off) ? s[t - off] : 0;
        __syncthreads();
        s[t] += x;
        __syncthreads();
    }
    if (t < nb) partial[t] = s[t] - v;   // exclusive block offsets
}

__global__ __launch_bounds__(1024) void scan_finalize(
    const int* __restrict__ deg, const int* __restrict__ inc,
    const int* __restrict__ partial, int* __restrict__ row_ptr,
    int* __restrict__ cursor, int N)
{
    int i = blockIdx.x * 1024 + threadIdx.x;
    if (i >= N) return;
    int v = inc[i] + partial[blockIdx.x];
    row_ptr[i + 1] = v;
    cursor[i] = v - deg[i];
    if (i == 0) row_ptr[0] = 0;
}

// per-edge: spline basis + precomputed gather byte-offsets (layer-invariant)
__global__ __launch_bounds__(256) void csr_scatter(
    const int* __restrict__ ei, const float* __restrict__ attr,
    int* __restrict__ cursor, int4* __restrict__ eoffs,
    float4* __restrict__ ebasis, int E)
{
    int e = blockIdx.x * 256 + threadIdx.x;
    if (e >= E) return;
    int src = ei[e], dst = ei[E + e];
    float u = attr[2 * e] * 4.f;
    float v = attr[2 * e + 1] * 4.f;
    float lu = floorf(u), lv = floorf(v);
    float fu = u - lu, fv = v - lv;
    int iu = (int)lu;  iu = iu < 0 ? 0 : (iu > 4 ? 4 : iu);
    int iv = (int)lv;  iv = iv < 0 ? 0 : (iv > 4 ? 4 : iv);
    int iu1 = iu + 1 > 4 ? 4 : iu + 1;
    int iv1 = iv + 1 > 4 ? 4 : iv + 1;
    int rb = src * 3200;                       // byte offset of row (1600 bf16)
    int pos = atomicAdd(&cursor[dst], 1);
    eoffs[pos] = make_int4(rb + (iu + 5 * iv) * 128, rb + (iu + 5 * iv1) * 128,
                           rb + (iu1 + 5 * iv) * 128, rb + (iu1 + 5 * iv1) * 128);
    ebasis[pos] = make_float4((1.f - fu) * (1.f - fv), (1.f - fu) * fv,
                              fu * (1.f - fv), fu * fv);
}

// ---------------- MFMA GEMM: xW (26 tiles; tile 25 = root, fp32) --------
__global__ __launch_bounds__(256) void gemm_xw(
    const ushort* __restrict__ A, const ushort* __restrict__ Wt,
    ushort* __restrict__ xWb, float* __restrict__ xRoot, int mtiles)
{
    __shared__ ushort Cs[64][72];   // 144 B/row: uint4-aligned, bank-spread
    const int bx = blockIdx.x;
    const int wave = threadIdx.x >> 6;
    const int lane = threadIdx.x & 63;
    const int l16 = lane & 15;
    const int half = lane >> 4;                 // 0..3
    const int tid = threadIdx.x;

    // B fragments once per wave (~32 VGPRs: deliberate — ILP)
    const ushort* btile = Wt + (size_t)bx * 4096;
    bf16x8 b0[4], b1[4];
    #pragma unroll
    for (int s = 0; s < 4; ++s) {
        const ushort* brow = btile + (size_t)(s * 16 + l16) * 64;
        b0[s] = *(const bf16x8*)(brow + half * 8);
        b1[s] = *(const bf16x8*)(brow + 32 + half * 8);
    }

    for (int it = 0; it < 4; ++it) {
        const int mt = blockIdx.y * 4 + it;
        if (mt >= mtiles) break;                 // block-uniform
        const int m0 = mt * 64;
        const int m_base = m0 + wave * 16;

        const ushort* arow = A + (size_t)(m_base + l16) * 64;
        bf16x8 a0 = *(const bf16x8*)(arow + half * 8);
        bf16x8 a1 = *(const bf16x8*)(arow + 32 + half * 8);

        f32x4 acc[4];
        #pragma unroll
        for (int s = 0; s < 4; ++s) {
            acc[s] = (f32x4){0.f, 0.f, 0.f, 0.f};
            acc[s] = __builtin_amdgcn_mfma_f32_16x16x32_bf16(a0, b0[s], acc[s], 0, 0, 0);
            acc[s] = __builtin_amdgcn_mfma_f32_16x16x32_bf16(a1, b1[s], acc[s], 0, 0, 0);
        }

        if (bx == 25) {   // root tile -> fp32 xRoot (padded ws, no guard)
            #pragma unroll
            for (int s = 0; s < 4; ++s)
                #pragma unroll
                for (int r = 0; r < 4; ++r)
                    xRoot[(size_t)(m_base + half * 4 + r) * 64 + s * 16 + l16] = acc[s][r];
            continue;
        }

        // bf16 tile -> LDS -> coalesced uint4 store
        #pragma unroll
        for (int s = 0; s < 4; ++s)
            #pragma unroll
            for (int r = 0; r < 4; ++r)
                Cs[wave * 16 + half * 4 + r][s * 16 + l16] = f2bf(acc[s][r]);
        __syncthreads();
        #pragma unroll
        for (int i2 = 0; i2 < 2; ++i2) {
            int idx = tid + i2 * 256;
            int row = idx >> 3, seg = idx & 7;
            uint4 v = *(const uint4*)&Cs[row][seg * 8];
            *(uint4*)(xWb + (size_t)(m0 + row) * 1600 + bx * 64 + seg * 8) = v;
        }
        __syncthreads();   // protect Cs against next iteration's writes
    }
}

// ---------------- edge pass: wave per dst, scalarized edge stream -------
__global__ __launch_bounds__(256) void edge_csr(
    const ushort* __restrict__ xWb, const int* __restrict__ row_ptr,
    const int4* __restrict__ eoffs, const float4* __restrict__ ebasis,
    const float* __restrict__ xRoot, const float* __restrict__ bias,
    float* __restrict__ outf, ushort* __restrict__ outb, int N)
{
    // Wave id forced into SGPR => d, e0, e1, loop counter, and all per-edge
    // loads (eoffs/ebasis) are scalar; gathers use SGPR-base + lane*2.
    const int wv = __builtin_amdgcn_readfirstlane(threadIdx.x >> 6);
    const int d = blockIdx.x * 4 + wv;
    const int lane = threadIdx.x & 63;
    if (d >= N) return;
    const int e0 = __builtin_amdgcn_readfirstlane(row_ptr[d]);
    const int e1 = __builtin_amdgcn_readfirstlane(row_ptr[d + 1]);
    const char* xwb = (const char*)xWb;
    const int lane2 = lane * 2;

    float vmax = -__builtin_inff();
    int e = e0;
    for (; e + 2 <= e1; e += 2) {
        int4 oa = eoffs[e];
        int4 ob = eoffs[e + 1];
        float4 ba = ebasis[e];
        float4 bb = ebasis[e + 1];
        float m0 = ba.x * bf2f(*(const ushort*)(xwb + oa.x + lane2));
        float m1 = bb.x * bf2f(*(const ushort*)(xwb + ob.x + lane2));
        m0 = fmaf(ba.y, bf2f(*(const ushort*)(xwb + oa.y + lane2)), m0);
        m1 = fmaf(bb.y, bf2f(*(const ushort*)(xwb + ob.y + lane2)), m1);
        m0 = fmaf(ba.z, bf2f(*(const ushort*)(xwb + oa.z + lane2)), m0);
        m1 = fmaf(bb.z, bf2f(*(const ushort*)(xwb + ob.z + lane2)), m1);
        m0 = fmaf(ba.w, bf2f(*(const ushort*)(xwb + oa.w + lane2)), m0);
        m1 = fmaf(bb.w, bf2f(*(const ushort*)(xwb + ob.w + lane2)), m1);
        vmax = fmaxf(vmax, fmaxf(m0, m1));
    }
    if (e < e1) {
        int4 oa = eoffs[e];
        float4 ba = ebasis[e];
        float m0 = ba.x * bf2f(*(const ushort*)(xwb + oa.x + lane2));
        m0 = fmaf(ba.y, bf2f(*(const ushort*)(xwb + oa.y + lane2)), m0);
        m0 = fmaf(ba.z, bf2f(*(const ushort*)(xwb + oa.z + lane2)), m0);
        m0 = fmaf(ba.w, bf2f(*(const ushort*)(xwb + oa.w + lane2)), m0);
        vmax = fmaxf(vmax, m0);
    }
    if (e1 == e0) vmax = 0.f;          // segment_max(-inf) -> 0
    float val = vmax + xRoot[(size_t)d * 64 + lane] + bias[lane];
    val = fmaxf(val, 0.f);
    outf[(size_t)d * 64 + lane] = val;
    if (outb) outb[(size_t)d * 64 + lane] = f2bf(val);
}

// ---------------- final: out = [x|x1|x2] @ fw + fb (fp32) ---------------
__global__ __launch_bounds__(256) void final_gemm(
    const float* __restrict__ x, const float* __restrict__ x1,
    const float* __restrict__ x2, const float* __restrict__ fw,
    const float* __restrict__ fb, float* __restrict__ out, int M)
{
    __shared__ float As[64][68];
    __shared__ float Bs[64][68];
    const int m0 = blockIdx.x * 64;
    const int tid = threadIdx.x;
    const int tx = tid & 15, ty = tid >> 4;
    float acc[4][4] = {};
    const float* srcs[3] = {x, x1, x2};

    for (int kt = 0; kt < 3; ++kt) {
        const float* A = srcs[kt];
        const float4* B4 = (const float4*)(fw + (size_t)kt * 4096);
        #pragma unroll
        for (int r = 0; r < 4; ++r) {
            int idx = tid + r * 256;
            float4 v = B4[idx];
            int i = idx >> 4;
            int o = (idx & 15) * 4;
            Bs[i][o] = v.x; Bs[i][o + 1] = v.y; Bs[i][o + 2] = v.z; Bs[i][o + 3] = v.w;
        }
        #pragma unroll
        for (int r = 0; r < 4; ++r) {
            int idx = tid + r * 256;
            int m = idx >> 4;
            int k = (idx & 15) * 4;
            int gm = m0 + m;
            float4 v = make_float4(0.f, 0.f, 0.f, 0.f);
            if (gm < M) v = *(const float4*)(A + (size_t)gm * 64 + k);
            As[k][m] = v.x; As[k + 1][m] = v.y; As[k + 2][m] = v.z; As[k + 3][m] = v.w;
        }
        __syncthreads();
        #pragma unroll 8
        for (int k = 0; k < 64; ++k) {
            float4 av = *(const float4*)&As[k][ty * 4];
            float4 bv = *(const float4*)&Bs[k][tx * 4];
            float aa[4] = {av.x, av.y, av.z, av.w};
            float bb[4] = {bv.x, bv.y, bv.z, bv.w};
            #pragma unroll
            for (int i = 0; i < 4; ++i)
                #pragma unroll
                for (int j = 0; j < 4; ++j)
                    acc[i][j] = fmaf(aa[i], bb[j], acc[i][j]);
        }
        __syncthreads();
    }

    #pragma unroll
    for (int i = 0; i < 4; ++i) {
        int gm = m0 + ty * 4 + i;
        if (gm < M) {
            float4 v = make_float4(acc[i][0] + fb[tx * 4 + 0],
                                   acc[i][1] + fb[tx * 4 + 1],
                                   acc[i][2] + fb[tx * 4 + 2],
                                   acc[i][3] + fb[tx * 4 + 3]);
            *(float4*)(out + (size_t)gm * 64 + tx * 4) = v;
        }
    }
}

extern "C" void kernel_launch(void* const* d_in, const int* in_sizes, int n_in,
                              void* d_out, int out_size, void* d_ws, size_t ws_size,
                              hipStream_t stream)
{
    const float* x    = (const float*)d_in[0];
    const int*   ei   = (const int*)d_in[1];
    const float* attr = (const float*)d_in[2];
    const float* W1   = (const float*)d_in[3];
    const float* r1   = (const float*)d_in[4];
    const float* b1   = (const float*)d_in[5];
    const float* W2   = (const float*)d_in[6];
    const float* r2   = (const float*)d_in[7];
    const float* b2   = (const float*)d_in[8];
    const float* fw   = (const float*)d_in[9];
    const float* fb   = (const float*)d_in[10];
    float* out = (float*)d_out;

    const int N = in_sizes[0] / 64;
    const int E = in_sizes[1] / 2;
    const int mtiles = (N + 63) / 64;
    const int Npad = mtiles * 64;

    // workspace carve (~220 MB; ws_size >= 358 MB per round-2 evidence)
    char* p = (char*)d_ws;
    auto alloc = [&](size_t bytes) { void* q = p; p += (bytes + 255) & ~(size_t)255; return q; };
    float4* ebasis = (float4*)alloc((size_t)E * 16);
    int4*   eoffs  = (int4*)alloc((size_t)E * 16);
    float*  x1f    = (float*)alloc((size_t)Npad * 64 * 4);
    float*  xRoot  = (float*)alloc((size_t)Npad * 64 * 4);
    ushort* xWb    = (ushort*)alloc((size_t)Npad * 1600 * 2);
    ushort* xb     = (ushort*)alloc((size_t)Npad * 64 * 2);
    ushort* x1b    = (ushort*)alloc((size_t)Npad * 64 * 2);
    ushort* WtA    = (ushort*)alloc((size_t)26 * 4096 * 2);
    ushort* WtB    = (ushort*)alloc((size_t)26 * 4096 * 2);
    int*    deg    = (int*)alloc((size_t)N * 4);
    int*    cursor = (int*)alloc((size_t)N * 4);
    int*    rowp   = (int*)alloc((size_t)(N + 1) * 4);
    int*    tmpinc = (int*)alloc((size_t)N * 4);
    int*    part   = (int*)alloc(64 * 4);

    const int nb = (N + 1023) / 1024;   // <= 64 for N <= 65536

    // converts (once per call)
    cvt_f32_bf16<<<(N * 64 + 255) / 256, 256, 0, stream>>>(x, xb, N * 64);
    cvt_WT<<<(26 * 4096 + 255) / 256, 256, 0, stream>>>(W1, r1, WtA);
    cvt_WT<<<(26 * 4096 + 255) / 256, 256, 0, stream>>>(W2, r2, WtB);

    // CSR build (once per call, reused by both layers)
    zero_ints<<<(N + 255) / 256, 256, 0, stream>>>(deg, N);
    hist_deg<<<(E + 255) / 256, 256, 0, stream>>>(ei, deg, E);
    scan_block<<<nb, 1024, 0, stream>>>(deg, tmpinc, part, N);
    scan_partial<<<1, 64, 0, stream>>>(part, nb);
    scan_finalize<<<nb, 1024, 0, stream>>>(deg, tmpinc, part, rowp, cursor, N);
    csr_scatter<<<(E + 255) / 256, 256, 0, stream>>>(ei, attr, cursor, eoffs, ebasis, E);

    const dim3 ggrid(26, (mtiles + 3) / 4);

    // layer 1
    gemm_xw<<<ggrid, 256, 0, stream>>>(xb, WtA, xWb, xRoot, mtiles);
    edge_csr<<<(N + 3) / 4, 256, 0, stream>>>(xWb, rowp, eoffs, ebasis, xRoot, b1, x1f, x1b, N);

    // layer 2 (x2 lives in d_out; final reads rows before writing them)
    gemm_xw<<<ggrid, 256, 0, stream>>>(x1b, WtB, xWb, xRoot, mtiles);
    edge_csr<<<(N + 3) / 4, 256, 0, stream>>>(xWb, rowp, eoffs, ebasis, xRoot, b2, out, nullptr, N);

    // final
    final_gemm<<<mtiles, 256, 0, stream>>>(x, x1f, out, fw, fb, out, N);
}

// Round 9
// 428.387 us; speedup vs baseline: 2.5943x; 1.0426x over previous
//
#include <hip/hip_runtime.h>
#include <hip/hip_bf16.h>

// SplineCNN round 9: fix __restrict__ aliasing UB in final_gemm.
// Round-8 evidence: call-1 correct (absmax 0.031) but post-timing diverged
// 3.44 => flaky, not static logic. Root cause: final_gemm took x2 and out
// as distinct __restrict__ pointers but was passed the SAME pointer (x2
// lived in d_out, in-place RMW). UB; recompile-sensitive reorder => wave-
// timing race. Fix: x2 gets its own ws buffer; final_gemm writes d_out
// exactly once (pure output). Round-8 perf features kept (packed epack,
// pipelined edge loop, 8-subtile gemm) — all validated on call 1.

typedef short  bf16x8 __attribute__((ext_vector_type(8)));
typedef float  f32x4  __attribute__((ext_vector_type(4)));

__device__ __forceinline__ float bf2f(ushort u) {
    return __uint_as_float((uint)u << 16);
}
__device__ __forceinline__ ushort f2bf(float f) {   // round-to-nearest-even
    uint u = __float_as_uint(f);
    return (ushort)((u + 0x7FFF + ((u >> 16) & 1)) >> 16);
}

// ---------------- converts ----------------------------------------------
__global__ __launch_bounds__(256) void cvt_f32_bf16(
    const float* __restrict__ in, ushort* __restrict__ out, int n)
{
    int i = blockIdx.x * 256 + threadIdx.x;
    if (i < n) out[i] = f2bf(in[i]);
}

// W[25][i][o] + root[i][o] (fp32) -> Wt[26][o][i] (bf16)
__global__ __launch_bounds__(256) void cvt_WT(
    const float* __restrict__ W, const float* __restrict__ root,
    ushort* __restrict__ Wt)
{
    int idx = blockIdx.x * 256 + threadIdx.x;
    if (idx >= 26 * 4096) return;
    int tile = idx >> 12, rem = idx & 4095, o = rem >> 6, i = rem & 63;
    float v = (tile < 25) ? W[tile * 4096 + i * 64 + o] : root[i * 64 + o];
    Wt[idx] = f2bf(v);
}

// ---------------- CSR build ---------------------------------------------
__global__ __launch_bounds__(256) void zero_ints(int* __restrict__ p, int n)
{
    int i = blockIdx.x * 256 + threadIdx.x;
    if (i < n) p[i] = 0;
}

__global__ __launch_bounds__(256) void hist_deg(
    const int* __restrict__ ei, int* __restrict__ deg, int E)
{
    int e = blockIdx.x * 256 + threadIdx.x;
    if (e < E) atomicAdd(&deg[ei[E + e]], 1);
}

__global__ __launch_bounds__(1024) void scan_block(
    const int* __restrict__ deg, int* __restrict__ inc,
    int* __restrict__ partial, int N)
{
    __shared__ int s[1024];
    int i = blockIdx.x * 1024 + threadIdx.x;
    int v = (i < N) ? deg[i] : 0;
    s[threadIdx.x] = v;
    __syncthreads();
    for (int off = 1; off < 1024; off <<= 1) {
        int t = (threadIdx.x >= off) ? s[threadIdx.x - off] : 0;
        __syncthreads();
        s[threadIdx.x] += t;
        __syncthreads();
    }
    if (i < N) inc[i] = s[threadIdx.x];
    if (threadIdx.x == 1023) partial[blockIdx.x] = s[1023];
}

__global__ void scan_partial(int* __restrict__ partial, int nb)  // nb <= 64
{
    __shared__ int s[64];
    int t = threadIdx.x;
    int v = (t < nb) ? partial[t] : 0;
    s[t] = v;
    __syncthreads();
    for (int off = 1; off < 64; off <<= 1) {
        int x = (t >= off) ? s[t - off] : 0;
        __syncthreads();
        s[t] += x;
        __syncthreads();
    }
    if (t < nb) partial[t] = s[t] - v;   // exclusive block offsets
}

__global__ __launch_bounds__(1024) void scan_finalize(
    const int* __restrict__ deg, const int* __restrict__ inc,
    const int* __restrict__ partial, int* __restrict__ row_ptr,
    int* __restrict__ cursor, int N)
{
    int i = blockIdx.x * 1024 + threadIdx.x;
    if (i >= N) return;
    int v = inc[i] + partial[blockIdx.x];
    row_ptr[i + 1] = v;
    cursor[i] = v - deg[i];
    if (i == 0) row_ptr[0] = 0;
}

// per-edge packed descriptor: {rb = src*3200, slots(4x8b), wlo(2xbf16), whi(2xbf16)}
__global__ __launch_bounds__(256) void csr_scatter(
    const int* __restrict__ ei, const float* __restrict__ attr,
    int* __restrict__ cursor, int4* __restrict__ epack, int E)
{
    int e = blockIdx.x * 256 + threadIdx.x;
    if (e >= E) return;
    int src = ei[e], dst = ei[E + e];
    float u = attr[2 * e] * 4.f;
    float v = attr[2 * e + 1] * 4.f;
    float lu = floorf(u), lv = floorf(v);
    float fu = u - lu, fv = v - lv;
    int iu = (int)lu;  iu = iu < 0 ? 0 : (iu > 4 ? 4 : iu);
    int iv = (int)lv;  iv = iv < 0 ? 0 : (iv > 4 ? 4 : iv);
    int iu1 = iu + 1 > 4 ? 4 : iu + 1;
    int iv1 = iv + 1 > 4 ? 4 : iv + 1;
    uint slots = (uint)(iu + 5 * iv) | ((uint)(iu + 5 * iv1) << 8) |
                 ((uint)(iu1 + 5 * iv) << 16) | ((uint)(iu1 + 5 * iv1) << 24);
    uint wlo = (uint)f2bf((1.f - fu) * (1.f - fv)) | ((uint)f2bf((1.f - fu) * fv) << 16);
    uint whi = (uint)f2bf(fu * (1.f - fv)) | ((uint)f2bf(fu * fv) << 16);
    int pos = atomicAdd(&cursor[dst], 1);
    epack[pos] = make_int4(src * 3200, (int)slots, (int)wlo, (int)whi);
}

// ---------------- MFMA GEMM: xW (26 tiles; tile 25 = root, fp32) --------
// 8 M-sub-tiles per block; B fragments in registers for the whole block.
__global__ __launch_bounds__(256) void gemm_xw(
    const ushort* __restrict__ A, const ushort* __restrict__ Wt,
    ushort* __restrict__ xWb, float* __restrict__ xRoot, int mtiles)
{
    __shared__ ushort Cs[64][72];   // 144 B/row: uint4-aligned, bank-spread
    const int bx = blockIdx.x;
    const int wave = threadIdx.x >> 6;
    const int lane = threadIdx.x & 63;
    const int l16 = lane & 15;
    const int half = lane >> 4;                 // 0..3
    const int tid = threadIdx.x;

    const ushort* btile = Wt + (size_t)bx * 4096;
    bf16x8 b0[4], b1[4];
    #pragma unroll
    for (int s = 0; s < 4; ++s) {
        const ushort* brow = btile + (size_t)(s * 16 + l16) * 64;
        b0[s] = *(const bf16x8*)(brow + half * 8);
        b1[s] = *(const bf16x8*)(brow + 32 + half * 8);
    }

    for (int it = 0; it < 8; ++it) {
        const int mt = blockIdx.y * 8 + it;
        if (mt >= mtiles) break;                 // block-uniform
        const int m0 = mt * 64;
        const int m_base = m0 + wave * 16;

        const ushort* arow = A + (size_t)(m_base + l16) * 64;
        bf16x8 a0 = *(const bf16x8*)(arow + half * 8);
        bf16x8 a1 = *(const bf16x8*)(arow + 32 + half * 8);

        f32x4 acc[4];
        #pragma unroll
        for (int s = 0; s < 4; ++s) {
            acc[s] = (f32x4){0.f, 0.f, 0.f, 0.f};
            acc[s] = __builtin_amdgcn_mfma_f32_16x16x32_bf16(a0, b0[s], acc[s], 0, 0, 0);
            acc[s] = __builtin_amdgcn_mfma_f32_16x16x32_bf16(a1, b1[s], acc[s], 0, 0, 0);
        }

        if (bx == 25) {   // root tile -> fp32 xRoot (padded ws, no guard)
            #pragma unroll
            for (int s = 0; s < 4; ++s)
                #pragma unroll
                for (int r = 0; r < 4; ++r)
                    xRoot[(size_t)(m_base + half * 4 + r) * 64 + s * 16 + l16] = acc[s][r];
            continue;
        }

        // bf16 tile -> LDS -> coalesced uint4 store
        #pragma unroll
        for (int s = 0; s < 4; ++s)
            #pragma unroll
            for (int r = 0; r < 4; ++r)
                Cs[wave * 16 + half * 4 + r][s * 16 + l16] = f2bf(acc[s][r]);
        __syncthreads();
        #pragma unroll
        for (int i2 = 0; i2 < 2; ++i2) {
            int idx = tid + i2 * 256;
            int row = idx >> 3, seg = idx & 7;
            uint4 v = *(const uint4*)&Cs[row][seg * 8];
            *(uint4*)(xWb + (size_t)(m0 + row) * 1600 + bx * 64 + seg * 8) = v;
        }
        __syncthreads();   // protect Cs against next iteration's writes
    }
}

// ---------------- edge pass: wave/dst, pipelined scalarized stream ------
__device__ __forceinline__ void gather4(
    const char* __restrict__ xwb, int lane, int rb, uint slots, ushort g[4])
{
    g[0] = *((const ushort*)(xwb + rb + ((slots & 255u) << 7)) + lane);
    g[1] = *((const ushort*)(xwb + rb + (((slots >> 8) & 255u) << 7)) + lane);
    g[2] = *((const ushort*)(xwb + rb + (((slots >> 16) & 255u) << 7)) + lane);
    g[3] = *((const ushort*)(xwb + rb + ((slots >> 24) << 7)) + lane);
}

__device__ __forceinline__ float consume4(const int4 d, const ushort g[4])
{
    float m = __uint_as_float((uint)d.z << 16) * bf2f(g[0]);
    m = fmaf(__uint_as_float((uint)d.z & 0xffff0000u), bf2f(g[1]), m);
    m = fmaf(__uint_as_float((uint)d.w << 16), bf2f(g[2]), m);
    m = fmaf(__uint_as_float((uint)d.w & 0xffff0000u), bf2f(g[3]), m);
    return m;
}

__global__ __launch_bounds__(256) void edge_csr(
    const ushort* __restrict__ xWb, const int* __restrict__ row_ptr,
    const int4* __restrict__ epack, const float* __restrict__ xRoot,
    const float* __restrict__ bias, float* __restrict__ outf,
    ushort* __restrict__ outb, int N)
{
    const int wv = __builtin_amdgcn_readfirstlane(threadIdx.x >> 6);
    const int d = blockIdx.x * 4 + wv;
    const int lane = threadIdx.x & 63;
    if (d >= N) return;
    const int e0 = __builtin_amdgcn_readfirstlane(row_ptr[d]);
    const int e1 = __builtin_amdgcn_readfirstlane(row_ptr[d + 1]);
    const char* xwb = (const char*)xWb;

    float vmax = -__builtin_inff();
    int e = e0;
    const int pairs = (e1 - e0) >> 1;
    if (pairs > 0) {
        // pipeline stage 0: descriptors + gathers for pair 0
        int4 dA = epack[e], dB = epack[e + 1];
        ushort gA[4], gB[4];
        gather4(xwb, lane, dA.x, (uint)dA.y, gA);
        gather4(xwb, lane, dB.x, (uint)dB.y, gB);
        for (int p = 1; p < pairs; ++p) {
            // issue next pair's loads before consuming current pair
            int4 nA = epack[e + 2 * p], nB = epack[e + 2 * p + 1];
            ushort hA[4], hB[4];
            gather4(xwb, lane, nA.x, (uint)nA.y, hA);
            gather4(xwb, lane, nB.x, (uint)nB.y, hB);
            vmax = fmaxf(vmax, fmaxf(consume4(dA, gA), consume4(dB, gB)));
            #pragma unroll
            for (int i = 0; i < 4; ++i) { gA[i] = hA[i]; gB[i] = hB[i]; }
            dA = nA; dB = nB;
        }
        vmax = fmaxf(vmax, fmaxf(consume4(dA, gA), consume4(dB, gB)));
        e += pairs * 2;
    }
    if (e < e1) {   // odd remainder
        int4 dA = epack[e];
        ushort gA[4];
        gather4(xwb, lane, dA.x, (uint)dA.y, gA);
        vmax = fmaxf(vmax, consume4(dA, gA));
    }
    if (e1 == e0) vmax = 0.f;          // segment_max(-inf) -> 0
    float val = vmax + xRoot[(size_t)d * 64 + lane] + bias[lane];
    val = fmaxf(val, 0.f);
    outf[(size_t)d * 64 + lane] = val;
    if (outb) outb[(size_t)d * 64 + lane] = f2bf(val);
}

// ---------------- final: out = [x|x1|x2] @ fw + fb (fp32) ---------------
// x, x1, x2, out are all DISTINCT buffers now (no aliasing; __restrict__
// is truthful; d_out is written exactly once, never read).
__global__ __launch_bounds__(256) void final_gemm(
    const float* __restrict__ x, const float* __restrict__ x1,
    const float* __restrict__ x2, const float* __restrict__ fw,
    const float* __restrict__ fb, float* __restrict__ out, int M)
{
    __shared__ float As[64][68];
    __shared__ float Bs[64][68];
    const int m0 = blockIdx.x * 64;
    const int tid = threadIdx.x;
    const int tx = tid & 15, ty = tid >> 4;
    float acc[4][4] = {};
    const float* srcs[3] = {x, x1, x2};

    for (int kt = 0; kt < 3; ++kt) {
        const float* A = srcs[kt];
        const float4* B4 = (const float4*)(fw + (size_t)kt * 4096);
        #pragma unroll
        for (int r = 0; r < 4; ++r) {
            int idx = tid + r * 256;
            float4 v = B4[idx];
            int i = idx >> 4;
            int o = (idx & 15) * 4;
            Bs[i][o] = v.x; Bs[i][o + 1] = v.y; Bs[i][o + 2] = v.z; Bs[i][o + 3] = v.w;
        }
        #pragma unroll
        for (int r = 0; r < 4; ++r) {
            int idx = tid + r * 256;
            int m = idx >> 4;
            int k = (idx & 15) * 4;
            int gm = m0 + m;
            float4 v = make_float4(0.f, 0.f, 0.f, 0.f);
            if (gm < M) v = *(const float4*)(A + (size_t)gm * 64 + k);
            As[k][m] = v.x; As[k + 1][m] = v.y; As[k + 2][m] = v.z; As[k + 3][m] = v.w;
        }
        __syncthreads();
        #pragma unroll 8
        for (int k = 0; k < 64; ++k) {
            float4 av = *(const float4*)&As[k][ty * 4];
            float4 bv = *(const float4*)&Bs[k][tx * 4];
            float aa[4] = {av.x, av.y, av.z, av.w};
            float bb[4] = {bv.x, bv.y, bv.z, bv.w};
            #pragma unroll
            for (int i = 0; i < 4; ++i)
                #pragma unroll
                for (int j = 0; j < 4; ++j)
                    acc[i][j] = fmaf(aa[i], bb[j], acc[i][j]);
        }
        __syncthreads();
    }

    #pragma unroll
    for (int i = 0; i < 4; ++i) {
        int gm = m0 + ty * 4 + i;
        if (gm < M) {
            float4 v = make_float4(acc[i][0] + fb[tx * 4 + 0],
                                   acc[i][1] + fb[tx * 4 + 1],
                                   acc[i][2] + fb[tx * 4 + 2],
                                   acc[i][3] + fb[tx * 4 + 3]);
            *(float4*)(out + (size_t)gm * 64 + tx * 4) = v;
        }
    }
}

extern "C" void kernel_launch(void* const* d_in, const int* in_sizes, int n_in,
                              void* d_out, int out_size, void* d_ws, size_t ws_size,
                              hipStream_t stream)
{
    const float* x    = (const float*)d_in[0];
    const int*   ei   = (const int*)d_in[1];
    const float* attr = (const float*)d_in[2];
    const float* W1   = (const float*)d_in[3];
    const float* r1   = (const float*)d_in[4];
    const float* b1   = (const float*)d_in[5];
    const float* W2   = (const float*)d_in[6];
    const float* r2   = (const float*)d_in[7];
    const float* b2   = (const float*)d_in[8];
    const float* fw   = (const float*)d_in[9];
    const float* fb   = (const float*)d_in[10];
    float* out = (float*)d_out;

    const int N = in_sizes[0] / 64;
    const int E = in_sizes[1] / 2;
    const int mtiles = (N + 63) / 64;
    const int Npad = mtiles * 64;

    // workspace carve (~225 MB; ws_size >= 358 MB per round-2 evidence)
    char* p = (char*)d_ws;
    auto alloc = [&](size_t bytes) { void* q = p; p += (bytes + 255) & ~(size_t)255; return q; };
    int4*   epack  = (int4*)alloc((size_t)E * 16);
    float*  x1f    = (float*)alloc((size_t)Npad * 64 * 4);
    float*  x2f    = (float*)alloc((size_t)Npad * 64 * 4);   // x2 no longer in d_out
    float*  xRoot  = (float*)alloc((size_t)Npad * 64 * 4);
    ushort* xWb    = (ushort*)alloc((size_t)Npad * 1600 * 2);
    ushort* xb     = (ushort*)alloc((size_t)Npad * 64 * 2);
    ushort* x1b    = (ushort*)alloc((size_t)Npad * 64 * 2);
    ushort* WtA    = (ushort*)alloc((size_t)26 * 4096 * 2);
    ushort* WtB    = (ushort*)alloc((size_t)26 * 4096 * 2);
    int*    deg    = (int*)alloc((size_t)N * 4);
    int*    cursor = (int*)alloc((size_t)N * 4);
    int*    rowp   = (int*)alloc((size_t)(N + 1) * 4);
    int*    tmpinc = (int*)alloc((size_t)N * 4);
    int*    part   = (int*)alloc(64 * 4);

    const int nb = (N + 1023) / 1024;   // <= 64 for N <= 65536

    // converts (once per call)
    cvt_f32_bf16<<<(N * 64 + 255) / 256, 256, 0, stream>>>(x, xb, N * 64);
    cvt_WT<<<(26 * 4096 + 255) / 256, 256, 0, stream>>>(W1, r1, WtA);
    cvt_WT<<<(26 * 4096 + 255) / 256, 256, 0, stream>>>(W2, r2, WtB);

    // CSR build (once per call, reused by both layers)
    zero_ints<<<(N + 255) / 256, 256, 0, stream>>>(deg, N);
    hist_deg<<<(E + 255) / 256, 256, 0, stream>>>(ei, deg, E);
    scan_block<<<nb, 1024, 0, stream>>>(deg, tmpinc, part, N);
    scan_partial<<<1, 64, 0, stream>>>(part, nb);
    scan_finalize<<<nb, 1024, 0, stream>>>(deg, tmpinc, part, rowp, cursor, N);
    csr_scatter<<<(E + 255) / 256, 256, 0, stream>>>(ei, attr, cursor, epack, E);

    const dim3 ggrid(26, (mtiles + 7) / 8);

    // layer 1
    gemm_xw<<<ggrid, 256, 0, stream>>>(xb, WtA, xWb, xRoot, mtiles);
    edge_csr<<<(N + 3) / 4, 256, 0, stream>>>(xWb, rowp, epack, xRoot, b1, x1f, x1b, N);

    // layer 2 (x2 -> x2f in ws; d_out untouched until final_gemm)
    gemm_xw<<<ggrid, 256, 0, stream>>>(x1b, WtB, xWb, xRoot, mtiles);
    edge_csr<<<(N + 3) / 4, 256, 0, stream>>>(xWb, rowp, epack, xRoot, b2, x2f, nullptr, N);

    // final: pure write to d_out
    final_gemm<<<mtiles, 256, 0, stream>>>(x, x1f, x2f, fw, fb, out, N);
}